// Round 2
// baseline (616.038 us; speedup 1.0000x reference)
//
#include <hip/hip_runtime.h>
#include <hip/hip_bf16.h>

// SA_fusion: B=4, C=512, H=W=64 (HW=4096), fp32 in/out.
// R8: ring-3 counted-vmcnt GEMM pipeline (T4). R7's 2-phase still drained
// vmcnt(0) every K-iter (the guide's m218: drain0 pipeline == no pipeline;
// counted vmcnt IS the gain). Now: 3 BK=32 LDS ring slots (48KB -> 3
// blocks/CU), iter t issues stage(t+2) then computes tile t, then waits
// s_waitcnt vmcnt(OPS) -- only tile t+1's loads must land; t+2's stay in
// flight ACROSS the barrier. One barrier per iter. K is a template param so
// the loop fully unrolls and ring indices/tail-waits constant-fold.
// setprio(1) around the MFMA cluster (T5). Applies to all 5 gemm_nt uses.

typedef _Float16 f16_t;
typedef _Float16 f16x8 __attribute__((ext_vector_type(8)));
typedef float f32x4 __attribute__((ext_vector_type(4)));

#define C_DIM 512
#define HW_DIM 4096
#define NBATCH 4
#define CHW (512L * 4096L)

__device__ inline f32x4 mfma_f16(f16x8 a, f16x8 b, f32x4 c) {
    return __builtin_amdgcn_mfma_f32_16x16x32_f16(a, b, c, 0, 0, 0);
}

// async 16B/lane global->LDS; lane i lands at base + i*16 (wave-uniform base).
__device__ inline void g2l16(const f16_t* g, f16_t* l) {
    auto gp = (const __attribute__((address_space(1))) uint32_t*)(uintptr_t)g;
    auto lp = (__attribute__((address_space(3))) uint32_t*)(uint32_t)(uintptr_t)l;
    __builtin_amdgcn_global_load_lds(gp, lp, 16, 0, 0);
}

// counted vmcnt wait, compile-time immediate, memory-clobbered so the
// compiler cannot move LDS reads across it.
template<int N> __device__ inline void vmwait() {
    static_assert(N == 0 || N == 3 || N == 4 || N == 6, "add vmcnt case");
    if constexpr (N == 0)      asm volatile("s_waitcnt vmcnt(0)" ::: "memory");
    else if constexpr (N == 3) asm volatile("s_waitcnt vmcnt(3)" ::: "memory");
    else if constexpr (N == 4) asm volatile("s_waitcnt vmcnt(4)" ::: "memory");
    else                       asm volatile("s_waitcnt vmcnt(6)" ::: "memory");
}

// ---------------- stats: mean + rstd (unbiased var, ddof=1) per (b,c) --------
__global__ __launch_bounds__(256) void stats_kernel(
    const float* __restrict__ xc, const float* __restrict__ xs,
    float* __restrict__ meanc, float* __restrict__ rstdc,
    float* __restrict__ means, float* __restrict__ rstds)
{
    int id = blockIdx.x;
    int bc = id & 2047;
    const float4* x = (const float4*)((id < 2048 ? xc : xs) + (size_t)bc * HW_DIM);
    int tid = threadIdx.x;
    float s = 0.f, ss = 0.f;
#pragma unroll
    for (int i = 0; i < 4; i++) {
        float4 v = x[tid + (i << 8)];
        s += v.x + v.y + v.z + v.w;
        ss += v.x * v.x + v.y * v.y + v.z * v.z + v.w * v.w;
    }
#pragma unroll
    for (int o = 32; o; o >>= 1) { s += __shfl_down(s, o); ss += __shfl_down(ss, o); }
    __shared__ float red[8];
    if ((tid & 63) == 0) { red[(tid >> 6) * 2] = s; red[(tid >> 6) * 2 + 1] = ss; }
    __syncthreads();
    if (tid == 0) {
        s  = red[0] + red[2] + red[4] + red[6];
        ss = red[1] + red[3] + red[5] + red[7];
        float mean = s * (1.0f / 4096.0f);
        float var  = (ss - 4096.0f * mean * mean) * (1.0f / 4095.0f);
        float rstd = rsqrtf(var + 1e-5f);
        if (id < 2048) { meanc[bc] = mean; rstdc[bc] = rstd; }
        else           { means[bc] = mean; rstds[bc] = rstd; }
    }
}

// ---------------- weight pack: fp32 -> fp16 + bias copy ----------------------
__global__ __launch_bounds__(256) void pack_w4_kernel(
    const float* __restrict__ w0, const float* __restrict__ w1,
    const float* __restrict__ w2, const float* __restrict__ w3,
    f16_t* __restrict__ h0, f16_t* __restrict__ h1,
    f16_t* __restrict__ h2, f16_t* __restrict__ h3,
    const float* __restrict__ bb0, const float* __restrict__ bb1,
    const float* __restrict__ bb2, const float* __restrict__ bb3,
    float* __restrict__ biasws)
{
    int which = blockIdx.y;
    const float* w = which == 0 ? w0 : which == 1 ? w1 : which == 2 ? w2 : w3;
    f16_t* h = which == 0 ? h0 : which == 1 ? h1 : which == 2 ? h2 : h3;
    const float* bs = which == 0 ? bb0 : which == 1 ? bb1 : which == 2 ? bb2 : bb3;
    int i = blockIdx.x * 256 + threadIdx.x;
    h[i] = (f16_t)w[i];
    if (i < C_DIM) biasws[which * C_DIM + i] = bs[i];
}

// ---------------- input pack: (B,C,HW) fp32 -> (B,HW,C) fp16, opt norm -------
__global__ __launch_bounds__(256) void pack_T_kernel(
    const float* __restrict__ xc, const float* __restrict__ xs,
    const float* __restrict__ meanc, const float* __restrict__ rstdc,
    const float* __restrict__ means, const float* __restrict__ rstds,
    f16_t* __restrict__ ch, f16_t* __restrict__ sh, f16_t* __restrict__ sraw)
{
    __shared__ float tile[32][33];
    int z = blockIdx.z;
    int b = z & 3, src = z >> 2;
    const float* x    = (src == 0) ? xc : xs;
    const float* mean = (src == 0) ? meanc : means;
    const float* rstd = (src == 0) ? rstdc : rstds;
    f16_t* oh = (src == 0) ? ch : (src == 1) ? sh : sraw;
    bool norm = (src < 2);

    int c0 = blockIdx.y * 32, p0 = blockIdx.x * 32;
    int tp = threadIdx.x & 31, tc8 = threadIdx.x >> 5;
    const float* xb = x + ((size_t)b * C_DIM + c0) * HW_DIM + p0;
#pragma unroll
    for (int it = 0; it < 4; it++) {
        int c = tc8 + it * 8;
        float v = xb[(size_t)c * HW_DIM + tp];
        if (norm) {
            float m = mean[b * C_DIM + c0 + c];
            float r = rstd[b * C_DIM + c0 + c];
            v = (v - m) * r;
        }
        tile[c][tp] = v;
    }
    __syncthreads();
    int wc = threadIdx.x & 31, wp8 = threadIdx.x >> 5;
    f16_t* ohb = oh + ((size_t)b * HW_DIM + p0) * C_DIM + c0;
#pragma unroll
    for (int it = 0; it < 4; it++) {
        int p = wp8 + it * 8;
        ohb[(size_t)p * C_DIM + wc] = (f16_t)tile[wc][p];
    }
}

// ---------------- row softmax: S fp32 (4096x4096) -> P fp16, normalized ------
__global__ __launch_bounds__(256) void softmax_rows(
    const float* __restrict__ S, f16_t* __restrict__ P)
{
    int row = blockIdx.x;
    int tid = threadIdx.x;
    int wave = tid >> 6, lane = tid & 63;
    const float4* sr = (const float4*)(S + (size_t)row * HW_DIM);
    float4 v[4];
    float mx = -3.4e38f;
#pragma unroll
    for (int i = 0; i < 4; i++) {
        v[i] = sr[tid + (i << 8)];
        mx = fmaxf(mx, fmaxf(fmaxf(v[i].x, v[i].y), fmaxf(v[i].z, v[i].w)));
    }
#pragma unroll
    for (int o = 32; o; o >>= 1) mx = fmaxf(mx, __shfl_down(mx, o));
    __shared__ float red[4];
    if (lane == 0) red[wave] = mx;
    __syncthreads();
    mx = fmaxf(fmaxf(red[0], red[1]), fmaxf(red[2], red[3]));
    float sum = 0.f;
#pragma unroll
    for (int i = 0; i < 4; i++) {
        v[i].x = __expf(v[i].x - mx); v[i].y = __expf(v[i].y - mx);
        v[i].z = __expf(v[i].z - mx); v[i].w = __expf(v[i].w - mx);
        sum += v[i].x + v[i].y + v[i].z + v[i].w;
    }
#pragma unroll
    for (int o = 32; o; o >>= 1) sum += __shfl_down(sum, o);
    __syncthreads();
    if (lane == 0) red[wave] = sum;
    __syncthreads();
    sum = red[0] + red[1] + red[2] + red[3];
    float inv = 1.0f / sum;
    uint2* pr = (uint2*)(P + (size_t)row * HW_DIM);
#pragma unroll
    for (int i = 0; i < 4; i++) {
        union { uint2 u; f16_t h[4]; } o;
        o.h[0] = (f16_t)(v[i].x * inv); o.h[1] = (f16_t)(v[i].y * inv);
        o.h[2] = (f16_t)(v[i].z * inv); o.h[3] = (f16_t)(v[i].w * inv);
        pr[tid + (i << 8)] = o.u;
    }
}

// ---------------- split-K reduce: frsT[q][c] = f16(sum of 4 fp32 partials) ---
__global__ __launch_bounds__(256) void reduce4_kernel(
    const float* __restrict__ part, f16_t* __restrict__ out)
{
    size_t i = (size_t)blockIdx.x * 256 + threadIdx.x;   // float4 index
    const float4* p0 = (const float4*)part;
    const float4* p1 = (const float4*)(part + CHW);
    const float4* p2 = (const float4*)(part + 2 * CHW);
    const float4* p3 = (const float4*)(part + 3 * CHW);
    float4 a = p0[i], b = p1[i], c = p2[i], d = p3[i];
    union { uint2 u; f16_t h[4]; } o;
    o.h[0] = (f16_t)(a.x + b.x + c.x + d.x);
    o.h[1] = (f16_t)(a.y + b.y + c.y + d.y);
    o.h[2] = (f16_t)(a.z + b.z + c.z + d.z);
    o.h[3] = (f16_t)(a.w + b.w + c.w + d.w);
    ((uint2*)out)[i] = o.u;
}

// ---------------- NT GEMM: C[m][n] = sum_k A[m][k]*B[n][k] -------------------
// fp16, 16x16x32 MFMA, block=256 (2x2 waves). Ring-3 LDS pipeline:
//   iter t: issue stage(t+2) -> ds_read/MFMA tile t -> vmcnt(OPS) [t+1's
//   loads landed, t+2's stay in flight] -> s_barrier.
// KT (loop K) is a template param: full unroll, constant ring indices, and
// the tail drains 4->0 with compile-time immediates. lda = row pitch of A/B
// (may exceed KT for split-K). QK: z encodes (sel=z>>2, batch=z&3).
// EPI: 0 fp32 [m][n] (+bias,+resid); 1 f16 [m][n] (+bias);
//      3 f16 transposed [n][m] (+bias); 4 fp32 transposed [n][m] (no bias).
template<int WM, int WN, int EPI, bool QK, int KT>
__global__ __launch_bounds__(256) void gemm_nt(
    const f16_t* __restrict__ Ah, const f16_t* __restrict__ Bh,
    void* __restrict__ Cout0,
    const float* __restrict__ bias, const float* __restrict__ resid,
    int lda, int ldc,
    long sAz, long sBz, long sCz, long sRz, long sAw, long sBw, long sCw)
{
    constexpr int BM = 2 * WM * 16;
    constexpr int BN = 2 * WN * 16;
    constexpr int BK = 32;
    constexpr int NIT = KT / BK;
    constexpr int BUFSZ = (BM + BN) * BK;      // f16 elems per ring slot
    constexpr int AOPS = BM / 64;              // per-thread g2l16 ops for A
    constexpr int BOPS = BN / 64;
    constexpr int OPS  = AOPS + BOPS;          // per-wave in-flight per stage
    __shared__ __align__(16) f16_t smem[3 * BUFSZ];

    const int tid  = threadIdx.x;
    const int wave = tid >> 6, lane = tid & 63;
    const int wm = (wave >> 1) * (WM * 16);
    const int wn = (wave & 1) * (WN * 16);
    const int fr = lane & 15;
    const int fk = (lane >> 4) * 8;
    const int srow = lane >> 2;          // row within 16-row staging segment
    const int scol = (lane & 3) * 8;     // elem offset within row (16B)

    const long mBlock = (long)blockIdx.y * BM;
    const long nBlock = (long)blockIdx.x * BN;
    const int zz = blockIdx.z;
    const int z   = QK ? (zz & 3) : zz;
    const int sel = QK ? (zz >> 2) : 0;
    const f16_t* Az = Ah + (size_t)z * sAz + (size_t)sel * sAw;
    const f16_t* Bz = Bh + (size_t)z * sBz + (size_t)sel * sBw;
    const float* biasp = bias ? (bias + (QK ? sel * C_DIM : 0)) : nullptr;

    const f16_t* gA = Az + (size_t)(mBlock + srow) * lda + scol;
    const f16_t* gB = Bz + (size_t)(nBlock + srow) * lda + scol;

    // loop-invariant per-thread staging sources + LDS elem offsets
    const f16_t* srcA[AOPS]; int dstA[AOPS];
    const f16_t* srcB[BOPS]; int dstB[BOPS];
#pragma unroll
    for (int i = 0; i < AOPS; i++) {
        int seg = i * 4 + wave;
        srcA[i] = gA + (size_t)seg * 16 * lda;
        dstA[i] = seg * 512;                       // 16 rows * 32 cols
    }
#pragma unroll
    for (int i = 0; i < BOPS; i++) {
        int seg = i * 4 + wave;
        srcB[i] = gB + (size_t)seg * 16 * lda;
        dstB[i] = BM * BK + seg * 512;
    }

    // stage tile t into ring slot (t % 3); k-offset folds into the address
    auto stage = [&](int t) {
        f16_t* dst = smem + (t % 3) * BUFSZ;
        const int k0 = t * BK;
#pragma unroll
        for (int i = 0; i < AOPS; i++) g2l16(srcA[i] + k0, dst + dstA[i]);
#pragma unroll
        for (int i = 0; i < BOPS; i++) g2l16(srcB[i] + k0, dst + dstB[i]);
    };

    f32x4 acc[WM][WN];
#pragma unroll
    for (int i = 0; i < WM; i++)
#pragma unroll
        for (int j = 0; j < WN; j++)
            acc[i][j] = (f32x4){0.f, 0.f, 0.f, 0.f};

    // prologue: tile 0 must be complete, tile 1 stays in flight
    stage(0);
    stage(1);
    vmwait<OPS>();
    __builtin_amdgcn_s_barrier();
    __builtin_amdgcn_sched_barrier(0);

#pragma unroll
    for (int t = 0; t < NIT; ++t) {
        if (t + 2 < NIT) {
            stage(t + 2);
            __builtin_amdgcn_sched_barrier(0);   // keep load-issue ahead
        }
        const f16_t* sA = smem + (t % 3) * BUFSZ;
        const f16_t* sB = sA + BM * BK;
        f16x8 af[WM], bf[WN];
#pragma unroll
        for (int i = 0; i < WM; i++)
            af[i] = *reinterpret_cast<const f16x8*>(sA + (wm + i * 16 + fr) * BK + fk);
#pragma unroll
        for (int j = 0; j < WN; j++)
            bf[j] = *reinterpret_cast<const f16x8*>(sB + (wn + j * 16 + fr) * BK + fk);
        __builtin_amdgcn_s_setprio(1);
#pragma unroll
        for (int i = 0; i < WM; i++)
#pragma unroll
            for (int j = 0; j < WN; j++)
                acc[i][j] = mfma_f16(af[i], bf[j], acc[i][j]);
        __builtin_amdgcn_s_setprio(0);

        if (t + 2 < NIT)      vmwait<OPS>();   // t+1 landed, t+2 in flight
        else if (t + 1 < NIT) vmwait<0>();     // drain for the last tile
        if (t + 1 < NIT) {
            __builtin_amdgcn_s_barrier();
            __builtin_amdgcn_sched_barrier(0);
        }
    }

    // epilogue. D layout: col(n)=lane&15, row(m)=(lane>>4)*4+reg
    const int col  = lane & 15;
    const int rowq = (lane >> 4) * 4;
    const size_t cbase = (size_t)z * sCz + (size_t)sel * sCw;
#pragma unroll
    for (int i = 0; i < WM; i++) {
        const long mb = mBlock + wm + i * 16 + rowq;
        float bv[4];
#pragma unroll
        for (int r = 0; r < 4; r++) bv[r] = biasp ? biasp[mb + r] : 0.0f;
#pragma unroll
        for (int j = 0; j < WN; j++) {
            const long n = nBlock + wn + j * 16 + col;
            float v[4];
#pragma unroll
            for (int r = 0; r < 4; r++) v[r] = acc[i][j][r] + bv[r];
            if constexpr (EPI == 0) {
                float* O = (float*)Cout0 + cbase;
                const float* R = resid ? (resid + (size_t)z * sRz) : nullptr;
#pragma unroll
                for (int r = 0; r < 4; r++) {
                    size_t off = (size_t)(mb + r) * ldc + n;
                    O[off] = v[r] + (R ? R[off] : 0.0f);
                }
            } else if constexpr (EPI == 1) {
                f16_t* O = (f16_t*)Cout0 + cbase;
#pragma unroll
                for (int r = 0; r < 4; r++) O[(size_t)(mb + r) * ldc + n] = (f16_t)v[r];
            } else if constexpr (EPI == 3) {
                alignas(8) f16_t h[4];
#pragma unroll
                for (int r = 0; r < 4; r++) h[r] = (f16_t)v[r];
                size_t offo = cbase + (size_t)n * ldc + mb;
                *reinterpret_cast<uint2*>((f16_t*)Cout0 + offo) = *reinterpret_cast<uint2*>(h);
            } else {   // EPI == 4: fp32 transposed partial
                alignas(16) float h[4];
#pragma unroll
                for (int r = 0; r < 4; r++) h[r] = v[r];
                size_t offo = cbase + (size_t)n * ldc + mb;
                *reinterpret_cast<float4*>((float*)Cout0 + offo) = *reinterpret_cast<float4*>(h);
            }
        }
    }
}

// ---------------------------------------------------------------------------
extern "C" void kernel_launch(void* const* d_in, const int* in_sizes, int n_in,
                              void* d_out, int out_size, void* d_ws, size_t ws_size,
                              hipStream_t stream)
{
    const float* x_fcc = (const float*)d_in[0];
    const float* x_fss = (const float*)d_in[1];
    const float* w1 = (const float*)d_in[2];
    const float* b1 = (const float*)d_in[3];
    const float* w2 = (const float*)d_in[4];
    const float* b2 = (const float*)d_in[5];
    const float* w3 = (const float*)d_in[6];
    const float* b3 = (const float*)d_in[7];
    const float* wrs = (const float*)d_in[8];
    const float* brs = (const float*)d_in[9];
    float* out = (float*)d_out;
    (void)n_in; (void)in_sizes; (void)out_size; (void)ws_size;

    char* base = (char*)d_ws;
    size_t off = 0;
    auto take = [&](size_t bytes) -> char* {
        char* p = base + off;
        off += (bytes + 255) & ~(size_t)255;
        return p;
    };
    const size_t WB = (size_t)C_DIM * C_DIM * sizeof(f16_t);    // 512 KB
    const size_t TB = (size_t)NBATCH * CHW * sizeof(f16_t);     // 16 MB
    const long  TBe = NBATCH * CHW;                             // 8388608 elems

    float* meanc = (float*)take(2048 * 4);
    float* rstdc = (float*)take(2048 * 4);
    float* means = (float*)take(2048 * 4);
    float* rstds = (float*)take(2048 * 4);
    float* biasws = (float*)take(4 * C_DIM * 4);
    // weights contiguous: w1h -> w2h sel stride = C_DIM*C_DIM elems
    f16_t* w1h = (f16_t*)take(WB);
    f16_t* w2h = (f16_t*)take(WB);
    f16_t* w3h = (f16_t*)take(WB);
    f16_t* wrh = (f16_t*)take(WB);
    // qT -> kT adjacent: C sel stride = TBe elems
    f16_t* qT = (f16_t*)take(TB);
    f16_t* kT = (f16_t*)take(TB);
    f16_t* vh   = (f16_t*)take(TB);
    f16_t* frsT = (f16_t*)take(TB);
    // 128 MB region: phase-1 packs xcT(16) xsT(16) xsrT(16) [dead after convs]
    // phase-2: S fp32 [0,64), P fp16 [64,96), split-K partials fp32 [96,128)
    char* packb = take(8 * TB);
    f16_t* xcT  = (f16_t*)(packb);
    f16_t* xsT  = (f16_t*)(packb + TB);
    f16_t* xsrT = (f16_t*)(packb + 2 * TB);
    float* Smat = (float*)(packb);
    f16_t* Pmat = (f16_t*)(packb + 4 * TB);
    float* Part = (float*)(packb + 6 * TB);
    // total ws: ~0.05 + 2 + 64 + 128 = ~194 MB (<= R2's proven 196 MB)

    dim3 blk(256);

    // 1. stats
    stats_kernel<<<dim3(4096), blk, 0, stream>>>(x_fcc, x_fss, meanc, rstdc, means, rstds);
    // 2. weight packs + bias copy
    pack_w4_kernel<<<dim3(1024, 4), blk, 0, stream>>>(
        w1, w2, w3, wrs, w1h, w2h, w3h, wrh, b1, b2, b3, brs, biasws);
    // 3. input packs (content norm, style norm, style raw)
    pack_T_kernel<<<dim3(128, 16, 12), blk, 0, stream>>>(
        x_fcc, x_fss, meanc, rstdc, means, rstds, xcT, xsT, xsrT);
    // 4. q+k convs merged: sel 0 = (w1, content)->qT; sel 1 = (w2, style)->kT
    gemm_nt<4, 4, 3, true, C_DIM><<<dim3(32, 4, 8), blk, 0, stream>>>(
        w1h, xcT, qT, biasws, nullptr, C_DIM, C_DIM,
        0L, CHW, CHW, 0L, (long)C_DIM * C_DIM, TBe, TBe);
    // 5. v conv: [c][p] layout
    gemm_nt<4, 4, 1, false, C_DIM><<<dim3(32, 4, 4), blk, 0, stream>>>(
        w3h, xsrT, vh, biasws + 2 * C_DIM, nullptr, C_DIM, HW_DIM,
        0L, CHW, CHW, 0L, 0L, 0L, 0L);
    // 6. per-batch attention
    for (int b = 0; b < NBATCH; b++) {
        // scores: S[q][k] = q . k  (1024 blocks, 4/CU)
        gemm_nt<4, 4, 0, false, C_DIM><<<dim3(32, 32, 1), blk, 0, stream>>>(
            qT + (size_t)b * CHW, kT + (size_t)b * CHW,
            Smat, nullptr, nullptr, C_DIM, HW_DIM,
            0L, 0L, 0L, 0L, 0L, 0L, 0L);
        softmax_rows<<<dim3(4096), blk, 0, stream>>>(Smat, Pmat);
        // PV split-K: z = split (k-offset z*1024), partial[z] fp32 [q][c]
        gemm_nt<2, 4, 4, false, 1024><<<dim3(32, 8, 4), blk, 0, stream>>>(
            vh + (size_t)b * CHW, Pmat,
            Part, nullptr, nullptr, HW_DIM, C_DIM,
            1024L, 1024L, CHW, 0L, 0L, 0L, 0L);
        // reduce 4 partials -> fp16 frsT[b]  (2048 blocks)
        reduce4_kernel<<<dim3(CHW / 1024), blk, 0, stream>>>(
            Part, frsT + (size_t)b * CHW);
    }
    // 7. final conv + bias + residual -> fp32 out
    gemm_nt<4, 4, 0, false, C_DIM><<<dim3(32, 4, 4), blk, 0, stream>>>(
        wrh, frsT, out, biasws + 3 * C_DIM, x_fcc, C_DIM, HW_DIM,
        0L, CHW, CHW, CHW, 0L, 0L, 0L);
}

// Round 3
// 599.254 us; speedup vs baseline: 1.0280x; 1.0280x over previous
//
#include <hip/hip_runtime.h>
#include <hip/hip_bf16.h>

// SA_fusion: B=4, C=512, H=W=64 (HW=4096), fp32 in/out.
// R9: XCD-aware 2D chunk swizzle (T1). R8's counters showed staging at
// ~9 B/cyc/CU with 256 MB of panel re-reads served by L3 (working set 8MB
// > 4MB per-XCD L2; FETCH only 27MB so HBM not involved): an L3-BW wall,
// not a schedule problem (R7/R8 schedule changes were ~neutral). Now each
// XCD gets contiguous 2D chunks of output tiles whose A+B panel footprint
// (2-3MB) fits its private L2: re-reads promote from L3 (~5.4 TB/s eff)
// to L2 (34.5 TB/s agg). Ring-3 counted-vmcnt schedule unchanged (clean
// A/B). Chunks: scores/PV 8x8, convs 16x4; all grids nwg%8==0, pow2.

typedef _Float16 f16_t;
typedef _Float16 f16x8 __attribute__((ext_vector_type(8)));
typedef float f32x4 __attribute__((ext_vector_type(4)));

#define C_DIM 512
#define HW_DIM 4096
#define NBATCH 4
#define CHW (512L * 4096L)

__device__ inline f32x4 mfma_f16(f16x8 a, f16x8 b, f32x4 c) {
    return __builtin_amdgcn_mfma_f32_16x16x32_f16(a, b, c, 0, 0, 0);
}

// async 16B/lane global->LDS; lane i lands at base + i*16 (wave-uniform base).
__device__ inline void g2l16(const f16_t* g, f16_t* l) {
    auto gp = (const __attribute__((address_space(1))) uint32_t*)(uintptr_t)g;
    auto lp = (__attribute__((address_space(3))) uint32_t*)(uint32_t)(uintptr_t)l;
    __builtin_amdgcn_global_load_lds(gp, lp, 16, 0, 0);
}

// counted vmcnt wait, compile-time immediate, memory-clobbered so the
// compiler cannot move LDS reads across it.
template<int N> __device__ inline void vmwait() {
    static_assert(N == 0 || N == 3 || N == 4 || N == 6, "add vmcnt case");
    if constexpr (N == 0)      asm volatile("s_waitcnt vmcnt(0)" ::: "memory");
    else if constexpr (N == 3) asm volatile("s_waitcnt vmcnt(3)" ::: "memory");
    else if constexpr (N == 4) asm volatile("s_waitcnt vmcnt(4)" ::: "memory");
    else                       asm volatile("s_waitcnt vmcnt(6)" ::: "memory");
}

// ---------------- stats: mean + rstd (unbiased var, ddof=1) per (b,c) --------
__global__ __launch_bounds__(256) void stats_kernel(
    const float* __restrict__ xc, const float* __restrict__ xs,
    float* __restrict__ meanc, float* __restrict__ rstdc,
    float* __restrict__ means, float* __restrict__ rstds)
{
    int id = blockIdx.x;
    int bc = id & 2047;
    const float4* x = (const float4*)((id < 2048 ? xc : xs) + (size_t)bc * HW_DIM);
    int tid = threadIdx.x;
    float s = 0.f, ss = 0.f;
#pragma unroll
    for (int i = 0; i < 4; i++) {
        float4 v = x[tid + (i << 8)];
        s += v.x + v.y + v.z + v.w;
        ss += v.x * v.x + v.y * v.y + v.z * v.z + v.w * v.w;
    }
#pragma unroll
    for (int o = 32; o; o >>= 1) { s += __shfl_down(s, o); ss += __shfl_down(ss, o); }
    __shared__ float red[8];
    if ((tid & 63) == 0) { red[(tid >> 6) * 2] = s; red[(tid >> 6) * 2 + 1] = ss; }
    __syncthreads();
    if (tid == 0) {
        s  = red[0] + red[2] + red[4] + red[6];
        ss = red[1] + red[3] + red[5] + red[7];
        float mean = s * (1.0f / 4096.0f);
        float var  = (ss - 4096.0f * mean * mean) * (1.0f / 4095.0f);
        float rstd = rsqrtf(var + 1e-5f);
        if (id < 2048) { meanc[bc] = mean; rstdc[bc] = rstd; }
        else           { means[bc] = mean; rstds[bc] = rstd; }
    }
}

// ---------------- weight pack: fp32 -> fp16 + bias copy ----------------------
__global__ __launch_bounds__(256) void pack_w4_kernel(
    const float* __restrict__ w0, const float* __restrict__ w1,
    const float* __restrict__ w2, const float* __restrict__ w3,
    f16_t* __restrict__ h0, f16_t* __restrict__ h1,
    f16_t* __restrict__ h2, f16_t* __restrict__ h3,
    const float* __restrict__ bb0, const float* __restrict__ bb1,
    const float* __restrict__ bb2, const float* __restrict__ bb3,
    float* __restrict__ biasws)
{
    int which = blockIdx.y;
    const float* w = which == 0 ? w0 : which == 1 ? w1 : which == 2 ? w2 : w3;
    f16_t* h = which == 0 ? h0 : which == 1 ? h1 : which == 2 ? h2 : h3;
    const float* bs = which == 0 ? bb0 : which == 1 ? bb1 : which == 2 ? bb2 : bb3;
    int i = blockIdx.x * 256 + threadIdx.x;
    h[i] = (f16_t)w[i];
    if (i < C_DIM) biasws[which * C_DIM + i] = bs[i];
}

// ---------------- input pack: (B,C,HW) fp32 -> (B,HW,C) fp16, opt norm -------
__global__ __launch_bounds__(256) void pack_T_kernel(
    const float* __restrict__ xc, const float* __restrict__ xs,
    const float* __restrict__ meanc, const float* __restrict__ rstdc,
    const float* __restrict__ means, const float* __restrict__ rstds,
    f16_t* __restrict__ ch, f16_t* __restrict__ sh, f16_t* __restrict__ sraw)
{
    __shared__ float tile[32][33];
    int z = blockIdx.z;
    int b = z & 3, src = z >> 2;
    const float* x    = (src == 0) ? xc : xs;
    const float* mean = (src == 0) ? meanc : means;
    const float* rstd = (src == 0) ? rstdc : rstds;
    f16_t* oh = (src == 0) ? ch : (src == 1) ? sh : sraw;
    bool norm = (src < 2);

    int c0 = blockIdx.y * 32, p0 = blockIdx.x * 32;
    int tp = threadIdx.x & 31, tc8 = threadIdx.x >> 5;
    const float* xb = x + ((size_t)b * C_DIM + c0) * HW_DIM + p0;
#pragma unroll
    for (int it = 0; it < 4; it++) {
        int c = tc8 + it * 8;
        float v = xb[(size_t)c * HW_DIM + tp];
        if (norm) {
            float m = mean[b * C_DIM + c0 + c];
            float r = rstd[b * C_DIM + c0 + c];
            v = (v - m) * r;
        }
        tile[c][tp] = v;
    }
    __syncthreads();
    int wc = threadIdx.x & 31, wp8 = threadIdx.x >> 5;
    f16_t* ohb = oh + ((size_t)b * HW_DIM + p0) * C_DIM + c0;
#pragma unroll
    for (int it = 0; it < 4; it++) {
        int p = wp8 + it * 8;
        ohb[(size_t)p * C_DIM + wc] = (f16_t)tile[wc][p];
    }
}

// ---------------- row softmax: S fp32 (4096x4096) -> P fp16, normalized ------
__global__ __launch_bounds__(256) void softmax_rows(
    const float* __restrict__ S, f16_t* __restrict__ P)
{
    int row = blockIdx.x;
    int tid = threadIdx.x;
    int wave = tid >> 6, lane = tid & 63;
    const float4* sr = (const float4*)(S + (size_t)row * HW_DIM);
    float4 v[4];
    float mx = -3.4e38f;
#pragma unroll
    for (int i = 0; i < 4; i++) {
        v[i] = sr[tid + (i << 8)];
        mx = fmaxf(mx, fmaxf(fmaxf(v[i].x, v[i].y), fmaxf(v[i].z, v[i].w)));
    }
#pragma unroll
    for (int o = 32; o; o >>= 1) mx = fmaxf(mx, __shfl_down(mx, o));
    __shared__ float red[4];
    if (lane == 0) red[wave] = mx;
    __syncthreads();
    mx = fmaxf(fmaxf(red[0], red[1]), fmaxf(red[2], red[3]));
    float sum = 0.f;
#pragma unroll
    for (int i = 0; i < 4; i++) {
        v[i].x = __expf(v[i].x - mx); v[i].y = __expf(v[i].y - mx);
        v[i].z = __expf(v[i].z - mx); v[i].w = __expf(v[i].w - mx);
        sum += v[i].x + v[i].y + v[i].z + v[i].w;
    }
#pragma unroll
    for (int o = 32; o; o >>= 1) sum += __shfl_down(sum, o);
    __syncthreads();
    if (lane == 0) red[wave] = sum;
    __syncthreads();
    sum = red[0] + red[1] + red[2] + red[3];
    float inv = 1.0f / sum;
    uint2* pr = (uint2*)(P + (size_t)row * HW_DIM);
#pragma unroll
    for (int i = 0; i < 4; i++) {
        union { uint2 u; f16_t h[4]; } o;
        o.h[0] = (f16_t)(v[i].x * inv); o.h[1] = (f16_t)(v[i].y * inv);
        o.h[2] = (f16_t)(v[i].z * inv); o.h[3] = (f16_t)(v[i].w * inv);
        pr[tid + (i << 8)] = o.u;
    }
}

// ---------------- split-K reduce: frsT[q][c] = f16(sum of 4 fp32 partials) ---
__global__ __launch_bounds__(256) void reduce4_kernel(
    const float* __restrict__ part, f16_t* __restrict__ out)
{
    size_t i = (size_t)blockIdx.x * 256 + threadIdx.x;   // float4 index
    const float4* p0 = (const float4*)part;
    const float4* p1 = (const float4*)(part + CHW);
    const float4* p2 = (const float4*)(part + 2 * CHW);
    const float4* p3 = (const float4*)(part + 3 * CHW);
    float4 a = p0[i], b = p1[i], c = p2[i], d = p3[i];
    union { uint2 u; f16_t h[4]; } o;
    o.h[0] = (f16_t)(a.x + b.x + c.x + d.x);
    o.h[1] = (f16_t)(a.y + b.y + c.y + d.y);
    o.h[2] = (f16_t)(a.z + b.z + c.z + d.z);
    o.h[3] = (f16_t)(a.w + b.w + c.w + d.w);
    ((uint2*)out)[i] = o.u;
}

// ---------------- NT GEMM: C[m][n] = sum_k A[m][k]*B[n][k] -------------------
// fp16, 16x16x32 MFMA, block=256 (2x2 waves). Ring-3 LDS pipeline with
// counted vmcnt (tile t+2 in flight across the barrier). KT (loop K) is a
// template param: full unroll, constant ring indices.
// CHX/CHY: XCD chunk swizzle -- each XCD processes contiguous CHX x CHY
// tile chunks (A+B panel footprint sized to fit 4MB per-XCD L2). 0 = off.
// Requires nwg % 8 == 0 and pow2 chunk factors.
// lda = row pitch of A/B (may exceed KT for split-K). QK: z encodes
// (sel=z>>2, batch=z&3).
// EPI: 0 fp32 [m][n] (+bias,+resid); 1 f16 [m][n] (+bias);
//      3 f16 transposed [n][m] (+bias); 4 fp32 transposed [n][m] (no bias).
template<int WM, int WN, int EPI, bool QK, int KT, int CHX, int CHY>
__global__ __launch_bounds__(256) void gemm_nt(
    const f16_t* __restrict__ Ah, const f16_t* __restrict__ Bh,
    void* __restrict__ Cout0,
    const float* __restrict__ bias, const float* __restrict__ resid,
    int lda, int ldc,
    long sAz, long sBz, long sCz, long sRz, long sAw, long sBw, long sCw)
{
    constexpr int BM = 2 * WM * 16;
    constexpr int BN = 2 * WN * 16;
    constexpr int BK = 32;
    constexpr int NIT = KT / BK;
    constexpr int BUFSZ = (BM + BN) * BK;      // f16 elems per ring slot
    constexpr int AOPS = BM / 64;              // per-thread g2l16 ops for A
    constexpr int BOPS = BN / 64;
    constexpr int OPS  = AOPS + BOPS;          // per-wave in-flight per stage
    __shared__ __align__(16) f16_t smem[3 * BUFSZ];

    // ---- XCD chunk swizzle: physical lin id -> logical (bx,by,bz) ----
    int bx, by, bz;
    if constexpr (CHX > 0) {
        const int nbx = gridDim.x, nby = gridDim.y, nbz = gridDim.z;
        const int lin = (blockIdx.z * nby + blockIdx.y) * nbx + blockIdx.x;
        const int nwg = nbx * nby * nbz;
        const int cpx = nwg >> 3;                       // blocks per XCD
        const int logical = (lin & 7) * cpx + (lin >> 3);
        constexpr int CHB = CHX * CHY;
        const int chunk  = logical / CHB;
        const int within = logical % CHB;
        const int cx = within % CHX, cy = within / CHX;
        const int chunks_x = nbx / CHX;
        const int chx = chunk % chunks_x;
        int t = chunk / chunks_x;
        const int chunks_y = nby / CHY;
        const int chy = t % chunks_y;
        bz = t / chunks_y;
        bx = chx * CHX + cx;
        by = chy * CHY + cy;
    } else {
        bx = blockIdx.x; by = blockIdx.y; bz = blockIdx.z;
    }

    const int tid  = threadIdx.x;
    const int wave = tid >> 6, lane = tid & 63;
    const int wm = (wave >> 1) * (WM * 16);
    const int wn = (wave & 1) * (WN * 16);
    const int fr = lane & 15;
    const int fk = (lane >> 4) * 8;
    const int srow = lane >> 2;          // row within 16-row staging segment
    const int scol = (lane & 3) * 8;     // elem offset within row (16B)

    const long mBlock = (long)by * BM;
    const long nBlock = (long)bx * BN;
    const int zz = bz;
    const int z   = QK ? (zz & 3) : zz;
    const int sel = QK ? (zz >> 2) : 0;
    const f16_t* Az = Ah + (size_t)z * sAz + (size_t)sel * sAw;
    const f16_t* Bz = Bh + (size_t)z * sBz + (size_t)sel * sBw;
    const float* biasp = bias ? (bias + (QK ? sel * C_DIM : 0)) : nullptr;

    const f16_t* gA = Az + (size_t)(mBlock + srow) * lda + scol;
    const f16_t* gB = Bz + (size_t)(nBlock + srow) * lda + scol;

    // loop-invariant per-thread staging sources + LDS elem offsets
    const f16_t* srcA[AOPS]; int dstA[AOPS];
    const f16_t* srcB[BOPS]; int dstB[BOPS];
#pragma unroll
    for (int i = 0; i < AOPS; i++) {
        int seg = i * 4 + wave;
        srcA[i] = gA + (size_t)seg * 16 * lda;
        dstA[i] = seg * 512;                       // 16 rows * 32 cols
    }
#pragma unroll
    for (int i = 0; i < BOPS; i++) {
        int seg = i * 4 + wave;
        srcB[i] = gB + (size_t)seg * 16 * lda;
        dstB[i] = BM * BK + seg * 512;
    }

    // stage tile t into ring slot (t % 3); k-offset folds into the address
    auto stage = [&](int t) {
        f16_t* dst = smem + (t % 3) * BUFSZ;
        const int k0 = t * BK;
#pragma unroll
        for (int i = 0; i < AOPS; i++) g2l16(srcA[i] + k0, dst + dstA[i]);
#pragma unroll
        for (int i = 0; i < BOPS; i++) g2l16(srcB[i] + k0, dst + dstB[i]);
    };

    f32x4 acc[WM][WN];
#pragma unroll
    for (int i = 0; i < WM; i++)
#pragma unroll
        for (int j = 0; j < WN; j++)
            acc[i][j] = (f32x4){0.f, 0.f, 0.f, 0.f};

    // prologue: tile 0 must be complete, tile 1 stays in flight
    stage(0);
    stage(1);
    vmwait<OPS>();
    __builtin_amdgcn_s_barrier();
    __builtin_amdgcn_sched_barrier(0);

#pragma unroll
    for (int t = 0; t < NIT; ++t) {
        if (t + 2 < NIT) {
            stage(t + 2);
            __builtin_amdgcn_sched_barrier(0);   // keep load-issue ahead
        }
        const f16_t* sA = smem + (t % 3) * BUFSZ;
        const f16_t* sB = sA + BM * BK;
        f16x8 af[WM], bf[WN];
#pragma unroll
        for (int i = 0; i < WM; i++)
            af[i] = *reinterpret_cast<const f16x8*>(sA + (wm + i * 16 + fr) * BK + fk);
#pragma unroll
        for (int j = 0; j < WN; j++)
            bf[j] = *reinterpret_cast<const f16x8*>(sB + (wn + j * 16 + fr) * BK + fk);
        __builtin_amdgcn_s_setprio(1);
#pragma unroll
        for (int i = 0; i < WM; i++)
#pragma unroll
            for (int j = 0; j < WN; j++)
                acc[i][j] = mfma_f16(af[i], bf[j], acc[i][j]);
        __builtin_amdgcn_s_setprio(0);

        if (t + 2 < NIT)      vmwait<OPS>();   // t+1 landed, t+2 in flight
        else if (t + 1 < NIT) vmwait<0>();     // drain for the last tile
        if (t + 1 < NIT) {
            __builtin_amdgcn_s_barrier();
            __builtin_amdgcn_sched_barrier(0);
        }
    }

    // epilogue. D layout: col(n)=lane&15, row(m)=(lane>>4)*4+reg
    const int col  = lane & 15;
    const int rowq = (lane >> 4) * 4;
    const size_t cbase = (size_t)z * sCz + (size_t)sel * sCw;
#pragma unroll
    for (int i = 0; i < WM; i++) {
        const long mb = mBlock + wm + i * 16 + rowq;
        float bv[4];
#pragma unroll
        for (int r = 0; r < 4; r++) bv[r] = biasp ? biasp[mb + r] : 0.0f;
#pragma unroll
        for (int j = 0; j < WN; j++) {
            const long n = nBlock + wn + j * 16 + col;
            float v[4];
#pragma unroll
            for (int r = 0; r < 4; r++) v[r] = acc[i][j][r] + bv[r];
            if constexpr (EPI == 0) {
                float* O = (float*)Cout0 + cbase;
                const float* R = resid ? (resid + (size_t)z * sRz) : nullptr;
#pragma unroll
                for (int r = 0; r < 4; r++) {
                    size_t off = (size_t)(mb + r) * ldc + n;
                    O[off] = v[r] + (R ? R[off] : 0.0f);
                }
            } else if constexpr (EPI == 1) {
                f16_t* O = (f16_t*)Cout0 + cbase;
#pragma unroll
                for (int r = 0; r < 4; r++) O[(size_t)(mb + r) * ldc + n] = (f16_t)v[r];
            } else if constexpr (EPI == 3) {
                alignas(8) f16_t h[4];
#pragma unroll
                for (int r = 0; r < 4; r++) h[r] = (f16_t)v[r];
                size_t offo = cbase + (size_t)n * ldc + mb;
                *reinterpret_cast<uint2*>((f16_t*)Cout0 + offo) = *reinterpret_cast<uint2*>(h);
            } else {   // EPI == 4: fp32 transposed partial
                alignas(16) float h[4];
#pragma unroll
                for (int r = 0; r < 4; r++) h[r] = v[r];
                size_t offo = cbase + (size_t)n * ldc + mb;
                *reinterpret_cast<float4*>((float*)Cout0 + offo) = *reinterpret_cast<float4*>(h);
            }
        }
    }
}

// ---------------------------------------------------------------------------
extern "C" void kernel_launch(void* const* d_in, const int* in_sizes, int n_in,
                              void* d_out, int out_size, void* d_ws, size_t ws_size,
                              hipStream_t stream)
{
    const float* x_fcc = (const float*)d_in[0];
    const float* x_fss = (const float*)d_in[1];
    const float* w1 = (const float*)d_in[2];
    const float* b1 = (const float*)d_in[3];
    const float* w2 = (const float*)d_in[4];
    const float* b2 = (const float*)d_in[5];
    const float* w3 = (const float*)d_in[6];
    const float* b3 = (const float*)d_in[7];
    const float* wrs = (const float*)d_in[8];
    const float* brs = (const float*)d_in[9];
    float* out = (float*)d_out;
    (void)n_in; (void)in_sizes; (void)out_size; (void)ws_size;

    char* base = (char*)d_ws;
    size_t off = 0;
    auto take = [&](size_t bytes) -> char* {
        char* p = base + off;
        off += (bytes + 255) & ~(size_t)255;
        return p;
    };
    const size_t WB = (size_t)C_DIM * C_DIM * sizeof(f16_t);    // 512 KB
    const size_t TB = (size_t)NBATCH * CHW * sizeof(f16_t);     // 16 MB
    const long  TBe = NBATCH * CHW;                             // 8388608 elems

    float* meanc = (float*)take(2048 * 4);
    float* rstdc = (float*)take(2048 * 4);
    float* means = (float*)take(2048 * 4);
    float* rstds = (float*)take(2048 * 4);
    float* biasws = (float*)take(4 * C_DIM * 4);
    // weights contiguous: w1h -> w2h sel stride = C_DIM*C_DIM elems
    f16_t* w1h = (f16_t*)take(WB);
    f16_t* w2h = (f16_t*)take(WB);
    f16_t* w3h = (f16_t*)take(WB);
    f16_t* wrh = (f16_t*)take(WB);
    // qT -> kT adjacent: C sel stride = TBe elems
    f16_t* qT = (f16_t*)take(TB);
    f16_t* kT = (f16_t*)take(TB);
    f16_t* vh   = (f16_t*)take(TB);
    f16_t* frsT = (f16_t*)take(TB);
    // 128 MB region: phase-1 packs xcT(16) xsT(16) xsrT(16) [dead after convs]
    // phase-2: S fp32 [0,64), P fp16 [64,96), split-K partials fp32 [96,128)
    char* packb = take(8 * TB);
    f16_t* xcT  = (f16_t*)(packb);
    f16_t* xsT  = (f16_t*)(packb + TB);
    f16_t* xsrT = (f16_t*)(packb + 2 * TB);
    float* Smat = (float*)(packb);
    f16_t* Pmat = (f16_t*)(packb + 4 * TB);
    float* Part = (float*)(packb + 6 * TB);
    // total ws: ~0.05 + 2 + 64 + 128 = ~194 MB (<= R2's proven 196 MB)

    dim3 blk(256);

    // 1. stats
    stats_kernel<<<dim3(4096), blk, 0, stream>>>(x_fcc, x_fss, meanc, rstdc, means, rstds);
    // 2. weight packs + bias copy
    pack_w4_kernel<<<dim3(1024, 4), blk, 0, stream>>>(
        w1, w2, w3, wrs, w1h, w2h, w3h, wrh, b1, b2, b3, brs, biasws);
    // 3. input packs (content norm, style norm, style raw)
    pack_T_kernel<<<dim3(128, 16, 12), blk, 0, stream>>>(
        x_fcc, x_fss, meanc, rstdc, means, rstds, xcT, xsT, xsrT);
    // 4. q+k convs merged: sel 0 = (w1, content)->qT; sel 1 = (w2, style)->kT
    //    chunk 16x4: B panels 16x128KB=2MB + A 512KB per XCD -> L2-fit
    gemm_nt<4, 4, 3, true, C_DIM, 16, 4><<<dim3(32, 4, 8), blk, 0, stream>>>(
        w1h, xcT, qT, biasws, nullptr, C_DIM, C_DIM,
        0L, CHW, CHW, 0L, (long)C_DIM * C_DIM, TBe, TBe);
    // 5. v conv: [c][p] layout, chunk 16x4
    gemm_nt<4, 4, 1, false, C_DIM, 16, 4><<<dim3(32, 4, 4), blk, 0, stream>>>(
        w3h, xsrT, vh, biasws + 2 * C_DIM, nullptr, C_DIM, HW_DIM,
        0L, CHW, CHW, 0L, 0L, 0L, 0L);
    // 6. per-batch attention
    for (int b = 0; b < NBATCH; b++) {
        // scores: S[q][k] = q . k  (1024 blocks; chunk 8x8 -> 2MB/XCD)
        gemm_nt<4, 4, 0, false, C_DIM, 8, 8><<<dim3(32, 32, 1), blk, 0, stream>>>(
            qT + (size_t)b * CHW, kT + (size_t)b * CHW,
            Smat, nullptr, nullptr, C_DIM, HW_DIM,
            0L, 0L, 0L, 0L, 0L, 0L, 0L);
        softmax_rows<<<dim3(4096), blk, 0, stream>>>(Smat, Pmat);
        // PV split-K: z = split (k-offset z*1024), partial[z] fp32 [q][c]
        //    chunk 8x8 (y capped at 8): A 1MB + B 2MB per XCD
        gemm_nt<2, 4, 4, false, 1024, 8, 8><<<dim3(32, 8, 4), blk, 0, stream>>>(
            vh + (size_t)b * CHW, Pmat,
            Part, nullptr, nullptr, HW_DIM, C_DIM,
            1024L, 1024L, CHW, 0L, 0L, 0L, 0L);
        // reduce 4 partials -> fp16 frsT[b]  (2048 blocks)
        reduce4_kernel<<<dim3(CHW / 1024), blk, 0, stream>>>(
            Part, frsT + (size_t)b * CHW);
    }
    // 7. final conv + bias + residual -> fp32 out, chunk 16x4
    gemm_nt<4, 4, 0, false, C_DIM, 16, 4><<<dim3(32, 4, 4), blk, 0, stream>>>(
        wrh, frsT, out, biasws + 3 * C_DIM, x_fcc, C_DIM, HW_DIM,
        0L, CHW, CHW, CHW, 0L, 0L, 0L);
}

// Round 4
// 557.871 us; speedup vs baseline: 1.1043x; 1.0742x over previous
//
#include <hip/hip_runtime.h>
#include <hip/hip_bf16.h>

// SA_fusion: B=4, C=512, H=W=64 (HW=4096), fp32 in/out.
// R10: new 512-thread phase-pipelined engine (gemm256) for scores, qk-conv,
// and PV. R9 post-mortem: our 128^2 engine runs 1650 cyc/block-iter vs m97's
// 736 at identical geometry -- the structure is the ceiling (and setprio/
// sched_barrier are documented regressions on it: m190/m141). gemm256 =
// BM256xBN128xBK64, 8 waves, ring-3 LDS 144KB (1 block/CU), 2 phases/tile
// with barrier-paired 16-MFMA clusters (T3), vmcnt(6) counted once per tile
// (T4), LDS granule-XOR swizzle via pre-swizzled global source + linear
// global_load_lds dest (T2, rule #21), setprio around MFMA (T5, pays on
// phase-split only). BK=64 rows = 128B full-line staging transactions.
// PV: split-K 4->8 (K=512/split, same NT=8 path), partials into dead S
// region, reduce8. v-conv + final conv keep the R9 engine.

typedef _Float16 f16_t;
typedef _Float16 f16x8 __attribute__((ext_vector_type(8)));
typedef float f32x4 __attribute__((ext_vector_type(4)));

#define C_DIM 512
#define HW_DIM 4096
#define NBATCH 4
#define CHW (512L * 4096L)

__device__ inline f32x4 mfma_f16(f16x8 a, f16x8 b, f32x4 c) {
    return __builtin_amdgcn_mfma_f32_16x16x32_f16(a, b, c, 0, 0, 0);
}

// async 16B/lane global->LDS; lane i lands at base + i*16 (wave-uniform base).
__device__ inline void g2l16(const f16_t* g, f16_t* l) {
    auto gp = (const __attribute__((address_space(1))) uint32_t*)(uintptr_t)g;
    auto lp = (__attribute__((address_space(3))) uint32_t*)(uint32_t)(uintptr_t)l;
    __builtin_amdgcn_global_load_lds(gp, lp, 16, 0, 0);
}

// counted vmcnt wait, compile-time immediate, memory-clobbered.
template<int N> __device__ inline void vmwait() {
    static_assert(N == 0 || N == 3 || N == 4 || N == 6, "add vmcnt case");
    if constexpr (N == 0)      asm volatile("s_waitcnt vmcnt(0)" ::: "memory");
    else if constexpr (N == 3) asm volatile("s_waitcnt vmcnt(3)" ::: "memory");
    else if constexpr (N == 4) asm volatile("s_waitcnt vmcnt(4)" ::: "memory");
    else                       asm volatile("s_waitcnt vmcnt(6)" ::: "memory");
}

__device__ inline void barrier_mem() {
    asm volatile("s_barrier" ::: "memory");
    __builtin_amdgcn_sched_barrier(0);
}

// ---------------- stats: mean + rstd (unbiased var, ddof=1) per (b,c) --------
__global__ __launch_bounds__(256) void stats_kernel(
    const float* __restrict__ xc, const float* __restrict__ xs,
    float* __restrict__ meanc, float* __restrict__ rstdc,
    float* __restrict__ means, float* __restrict__ rstds)
{
    int id = blockIdx.x;
    int bc = id & 2047;
    const float4* x = (const float4*)((id < 2048 ? xc : xs) + (size_t)bc * HW_DIM);
    int tid = threadIdx.x;
    float s = 0.f, ss = 0.f;
#pragma unroll
    for (int i = 0; i < 4; i++) {
        float4 v = x[tid + (i << 8)];
        s += v.x + v.y + v.z + v.w;
        ss += v.x * v.x + v.y * v.y + v.z * v.z + v.w * v.w;
    }
#pragma unroll
    for (int o = 32; o; o >>= 1) { s += __shfl_down(s, o); ss += __shfl_down(ss, o); }
    __shared__ float red[8];
    if ((tid & 63) == 0) { red[(tid >> 6) * 2] = s; red[(tid >> 6) * 2 + 1] = ss; }
    __syncthreads();
    if (tid == 0) {
        s  = red[0] + red[2] + red[4] + red[6];
        ss = red[1] + red[3] + red[5] + red[7];
        float mean = s * (1.0f / 4096.0f);
        float var  = (ss - 4096.0f * mean * mean) * (1.0f / 4095.0f);
        float rstd = rsqrtf(var + 1e-5f);
        if (id < 2048) { meanc[bc] = mean; rstdc[bc] = rstd; }
        else           { means[bc] = mean; rstds[bc] = rstd; }
    }
}

// ---------------- weight pack: fp32 -> fp16 + bias copy ----------------------
__global__ __launch_bounds__(256) void pack_w4_kernel(
    const float* __restrict__ w0, const float* __restrict__ w1,
    const float* __restrict__ w2, const float* __restrict__ w3,
    f16_t* __restrict__ h0, f16_t* __restrict__ h1,
    f16_t* __restrict__ h2, f16_t* __restrict__ h3,
    const float* __restrict__ bb0, const float* __restrict__ bb1,
    const float* __restrict__ bb2, const float* __restrict__ bb3,
    float* __restrict__ biasws)
{
    int which = blockIdx.y;
    const float* w = which == 0 ? w0 : which == 1 ? w1 : which == 2 ? w2 : w3;
    f16_t* h = which == 0 ? h0 : which == 1 ? h1 : which == 2 ? h2 : h3;
    const float* bs = which == 0 ? bb0 : which == 1 ? bb1 : which == 2 ? bb2 : bb3;
    int i = blockIdx.x * 256 + threadIdx.x;
    h[i] = (f16_t)w[i];
    if (i < C_DIM) biasws[which * C_DIM + i] = bs[i];
}

// ---------------- input pack: (B,C,HW) fp32 -> (B,HW,C) fp16, opt norm -------
__global__ __launch_bounds__(256) void pack_T_kernel(
    const float* __restrict__ xc, const float* __restrict__ xs,
    const float* __restrict__ meanc, const float* __restrict__ rstdc,
    const float* __restrict__ means, const float* __restrict__ rstds,
    f16_t* __restrict__ ch, f16_t* __restrict__ sh, f16_t* __restrict__ sraw)
{
    __shared__ float tile[32][33];
    int z = blockIdx.z;
    int b = z & 3, src = z >> 2;
    const float* x    = (src == 0) ? xc : xs;
    const float* mean = (src == 0) ? meanc : means;
    const float* rstd = (src == 0) ? rstdc : rstds;
    f16_t* oh = (src == 0) ? ch : (src == 1) ? sh : sraw;
    bool norm = (src < 2);

    int c0 = blockIdx.y * 32, p0 = blockIdx.x * 32;
    int tp = threadIdx.x & 31, tc8 = threadIdx.x >> 5;
    const float* xb = x + ((size_t)b * C_DIM + c0) * HW_DIM + p0;
#pragma unroll
    for (int it = 0; it < 4; it++) {
        int c = tc8 + it * 8;
        float v = xb[(size_t)c * HW_DIM + tp];
        if (norm) {
            float m = mean[b * C_DIM + c0 + c];
            float r = rstd[b * C_DIM + c0 + c];
            v = (v - m) * r;
        }
        tile[c][tp] = v;
    }
    __syncthreads();
    int wc = threadIdx.x & 31, wp8 = threadIdx.x >> 5;
    f16_t* ohb = oh + ((size_t)b * HW_DIM + p0) * C_DIM + c0;
#pragma unroll
    for (int it = 0; it < 4; it++) {
        int p = wp8 + it * 8;
        ohb[(size_t)p * C_DIM + wc] = (f16_t)tile[wc][p];
    }
}

// ---------------- row softmax: S fp32 (4096x4096) -> P fp16, normalized ------
__global__ __launch_bounds__(256) void softmax_rows(
    const float* __restrict__ S, f16_t* __restrict__ P)
{
    int row = blockIdx.x;
    int tid = threadIdx.x;
    int wave = tid >> 6, lane = tid & 63;
    const float4* sr = (const float4*)(S + (size_t)row * HW_DIM);
    float4 v[4];
    float mx = -3.4e38f;
#pragma unroll
    for (int i = 0; i < 4; i++) {
        v[i] = sr[tid + (i << 8)];
        mx = fmaxf(mx, fmaxf(fmaxf(v[i].x, v[i].y), fmaxf(v[i].z, v[i].w)));
    }
#pragma unroll
    for (int o = 32; o; o >>= 1) mx = fmaxf(mx, __shfl_down(mx, o));
    __shared__ float red[4];
    if (lane == 0) red[wave] = mx;
    __syncthreads();
    mx = fmaxf(fmaxf(red[0], red[1]), fmaxf(red[2], red[3]));
    float sum = 0.f;
#pragma unroll
    for (int i = 0; i < 4; i++) {
        v[i].x = __expf(v[i].x - mx); v[i].y = __expf(v[i].y - mx);
        v[i].z = __expf(v[i].z - mx); v[i].w = __expf(v[i].w - mx);
        sum += v[i].x + v[i].y + v[i].z + v[i].w;
    }
#pragma unroll
    for (int o = 32; o; o >>= 1) sum += __shfl_down(sum, o);
    __syncthreads();
    if (lane == 0) red[wave] = sum;
    __syncthreads();
    sum = red[0] + red[1] + red[2] + red[3];
    float inv = 1.0f / sum;
    uint2* pr = (uint2*)(P + (size_t)row * HW_DIM);
#pragma unroll
    for (int i = 0; i < 4; i++) {
        union { uint2 u; f16_t h[4]; } o;
        o.h[0] = (f16_t)(v[i].x * inv); o.h[1] = (f16_t)(v[i].y * inv);
        o.h[2] = (f16_t)(v[i].z * inv); o.h[3] = (f16_t)(v[i].w * inv);
        pr[tid + (i << 8)] = o.u;
    }
}

// ---------------- split-K reduce: frsT[q][c] = f16(sum of 8 fp32 partials) ---
__global__ __launch_bounds__(256) void reduce8_kernel(
    const float* __restrict__ part, f16_t* __restrict__ out)
{
    size_t i = (size_t)blockIdx.x * 256 + threadIdx.x;   // float4 index
    float4 s = ((const float4*)part)[i];
#pragma unroll
    for (int p = 1; p < 8; p++) {
        float4 v = ((const float4*)(part + (size_t)p * CHW))[i];
        s.x += v.x; s.y += v.y; s.z += v.z; s.w += v.w;
    }
    union { uint2 u; f16_t h[4]; } o;
    o.h[0] = (f16_t)s.x; o.h[1] = (f16_t)s.y;
    o.h[2] = (f16_t)s.z; o.h[3] = (f16_t)s.w;
    ((uint2*)out)[i] = o.u;
}

// ================= gemm256: phase-pipelined NT GEMM (K = 512) ================
// C[m][n] = sum_k A[m][k]*B[n][k]. BM=256, BN=128, BK=64, 512 threads
// (8 waves: 2 M-groups x 4 N-groups; per-wave output 128x32, acc[8][2]).
// Ring-3 LDS (3 x 48KB = 144KB, 1 block/CU). Per K-tile: 2 phases (k-slices),
// each {ds_read frags; stage unit of tile t+2; [vmcnt(6) @p1]; barrier;
// setprio(1); 16 MFMA; setprio(0); barrier}. Staging: A = 32 instrs of
// 8 rows x 128B (full cache lines), wave w -> instrs 4w..4w+3 (phase 0);
// B = 16 instrs, wave w -> 2w,2w+1 (phase 1). LDS swizzle (T2): slot
// (row, g) holds source 16B-granule g ^ (row&7); write side realized by
// pre-swizzled per-lane GLOBAL source (linear LDS dest, rule #21); read
// side XORs the granule. EPI: 0 fp32 [m][n]; 3 f16 T [n][m] (+bias);
// 4 fp32 T [n][m]. QK: z encodes (sel=z>>2, batch=z&3).
template<int EPI, bool QK, int CHX, int CHY>
__global__ __launch_bounds__(512, 2) void gemm256(
    const f16_t* __restrict__ Ah, const f16_t* __restrict__ Bh,
    void* __restrict__ Cout0, const float* __restrict__ bias,
    int lda, int ldc,
    long sAz, long sBz, long sCz, long sAw, long sBw, long sCw)
{
    constexpr int NT = 8;               // K = 512 = 8 x BK64
    constexpr int AE = 256 * 64;        // A elems/tile = 16384 (32KB)
    constexpr int BE = 128 * 64;        // B elems/tile = 8192  (16KB)
    constexpr int BUFE = AE + BE;       // 24576 elems = 48KB/slot
    __shared__ __align__(16) f16_t smem[3 * BUFE];   // 144KB

    // ---- XCD chunk swizzle (bijective; nwg % 8 == 0, pow2 chunks) ----
    int bx, by, bz;
    {
        const int nbx = gridDim.x, nby = gridDim.y, nbz = gridDim.z;
        const int lin = ((int)blockIdx.z * nby + blockIdx.y) * nbx + blockIdx.x;
        const int nwg = nbx * nby * nbz;
        const int cpx = nwg >> 3;
        const int logical = (lin & 7) * cpx + (lin >> 3);
        constexpr int CHB = CHX * CHY;
        const int chunk  = logical / CHB;
        const int within = logical % CHB;
        const int cx = within % CHX, cy = within / CHX;
        const int chunks_x = nbx / CHX;
        const int chx = chunk % chunks_x;
        int tt = chunk / chunks_x;
        const int chunks_y = nby / CHY;
        bz = tt / chunks_y;
        by = (tt % chunks_y) * CHY + cy;
        bx = chx * CHX + cx;
    }

    const int tid  = threadIdx.x;
    const int wave = tid >> 6, lane = tid & 63;
    const int wm = (wave >> 2) * 128;    // M-group rows
    const int wn = (wave & 3) * 32;      // N-group cols
    const int fr = lane & 15;
    const int g16 = lane >> 4;           // 0..3, frag k-granule base
    const int key = fr & 7;              // read-side swizzle key

    const int z   = QK ? (bz & 3) : bz;
    const int sel = QK ? (bz >> 2) : 0;
    const f16_t* Az = Ah + (size_t)z * sAz + (size_t)sel * sAw;
    const f16_t* Bz = Bh + (size_t)z * sBz + (size_t)sel * sBw;
    const float* biasp = bias ? (bias + (QK ? sel * C_DIM : 0)) : nullptr;
    const long mBlock = (long)by * 256;
    const long nBlock = (long)bx * 128;

    // staging: per instr 8 rows x 128B; lane l -> row +(l>>3), LDS granule
    // l&7; pre-swizzled source granule (l&7)^(l>>3)  [slot g <- src g^(row&7)]
    const int srow8 = lane >> 3;
    const int gsrc  = ((lane & 7) ^ srow8) * 8;   // f16 elems
    const f16_t* aSrc[4]; const f16_t* bSrc[2];
    int aDst[4], bDst[2];
#pragma unroll
    for (int q = 0; q < 4; q++) {
        int j = 4 * wave + q;
        aSrc[q] = Az + (size_t)(mBlock + 8 * j + srow8) * lda + gsrc;
        aDst[q] = j * 512;
    }
#pragma unroll
    for (int q = 0; q < 2; q++) {
        int j = 2 * wave + q;
        bSrc[q] = Bz + (size_t)(nBlock + 8 * j + srow8) * lda + gsrc;
        bDst[q] = AE + j * 512;
    }

    auto stageA = [&](int t) {
        f16_t* dst = smem + (t % 3) * BUFE;
        const int k0 = t * 64;
#pragma unroll
        for (int q = 0; q < 4; q++) g2l16(aSrc[q] + k0, dst + aDst[q]);
    };
    auto stageB = [&](int t) {
        f16_t* dst = smem + (t % 3) * BUFE;
        const int k0 = t * 64;
#pragma unroll
        for (int q = 0; q < 2; q++) g2l16(bSrc[q] + k0, dst + bDst[q]);
    };

    f32x4 acc[8][2];
#pragma unroll
    for (int i = 0; i < 8; i++)
#pragma unroll
        for (int j = 0; j < 2; j++) acc[i][j] = (f32x4){0.f, 0.f, 0.f, 0.f};

    // prologue: tiles 0,1 issued; tile 0 complete, tile 1 (6 loads) in flight
    stageA(0); stageB(0); stageA(1); stageB(1);
    vmwait<6>();
    barrier_mem();

#pragma unroll
    for (int t = 0; t < NT; ++t) {
        const f16_t* buf = smem + (t % 3) * BUFE;
#pragma unroll
        for (int ks = 0; ks < 2; ++ks) {
            f16x8 a[8], b[2];
            const int gr = ((ks * 4 + g16) ^ key) * 8;   // swizzled granule
#pragma unroll
            for (int j2 = 0; j2 < 2; j2++)
                b[j2] = *reinterpret_cast<const f16x8*>(
                    buf + AE + (wn + j2 * 16 + fr) * 64 + gr);
#pragma unroll
            for (int mi = 0; mi < 8; mi++)
                a[mi] = *reinterpret_cast<const f16x8*>(
                    buf + (wm + mi * 16 + fr) * 64 + gr);
            if (t + 2 < NT) { if (ks == 0) stageA(t + 2); else stageB(t + 2); }
            if (ks == 1) {
                if (t + 2 < NT)      vmwait<6>();   // t+1 landed, t+2 in flight
                else if (t + 1 < NT) vmwait<0>();   // drain for last tile
            }
            barrier_mem();
            __builtin_amdgcn_s_setprio(1);
#pragma unroll
            for (int mi = 0; mi < 8; mi++)
#pragma unroll
                for (int j2 = 0; j2 < 2; j2++)
                    acc[mi][j2] = mfma_f16(a[mi], b[j2], acc[mi][j2]);
            __builtin_amdgcn_s_setprio(0);
            barrier_mem();
        }
    }

    // epilogue. D layout: col(n)=lane&15, row(m)=(lane>>4)*4+reg
    const int col  = lane & 15;
    const int rowq = (lane >> 4) * 4;
    const size_t cbase = (size_t)z * sCz + (size_t)sel * sCw;
#pragma unroll
    for (int mi = 0; mi < 8; mi++) {
        const long mb = mBlock + wm + mi * 16 + rowq;
        float bv[4];
#pragma unroll
        for (int r = 0; r < 4; r++) bv[r] = biasp ? biasp[mb + r] : 0.0f;
#pragma unroll
        for (int j2 = 0; j2 < 2; j2++) {
            const long n = nBlock + wn + j2 * 16 + col;
            float v[4];
#pragma unroll
            for (int r = 0; r < 4; r++) v[r] = acc[mi][j2][r] + bv[r];
            if constexpr (EPI == 0) {
                float* O = (float*)Cout0 + cbase;
#pragma unroll
                for (int r = 0; r < 4; r++) O[(size_t)(mb + r) * ldc + n] = v[r];
            } else if constexpr (EPI == 3) {
                alignas(8) f16_t h[4];
#pragma unroll
                for (int r = 0; r < 4; r++) h[r] = (f16_t)v[r];
                *reinterpret_cast<uint2*>((f16_t*)Cout0 + cbase + (size_t)n * ldc + mb)
                    = *reinterpret_cast<uint2*>(h);
            } else {   // EPI == 4: fp32 transposed partial
                alignas(16) float h[4];
#pragma unroll
                for (int r = 0; r < 4; r++) h[r] = v[r];
                *reinterpret_cast<float4*>((float*)Cout0 + cbase + (size_t)n * ldc + mb)
                    = *reinterpret_cast<float4*>(h);
            }
        }
    }
}

// ================= old 256-thread engine (v conv, final conv) ================
template<int WM, int WN, int EPI, bool QK, int KT, int CHX, int CHY>
__global__ __launch_bounds__(256) void gemm_nt(
    const f16_t* __restrict__ Ah, const f16_t* __restrict__ Bh,
    void* __restrict__ Cout0,
    const float* __restrict__ bias, const float* __restrict__ resid,
    int lda, int ldc,
    long sAz, long sBz, long sCz, long sRz, long sAw, long sBw, long sCw)
{
    constexpr int BM = 2 * WM * 16;
    constexpr int BN = 2 * WN * 16;
    constexpr int BK = 32;
    constexpr int NIT = KT / BK;
    constexpr int BUFSZ = (BM + BN) * BK;
    constexpr int AOPS = BM / 64;
    constexpr int BOPS = BN / 64;
    constexpr int OPS  = AOPS + BOPS;
    __shared__ __align__(16) f16_t smem[3 * BUFSZ];

    int bx, by, bz;
    if constexpr (CHX > 0) {
        const int nbx = gridDim.x, nby = gridDim.y, nbz = gridDim.z;
        const int lin = (blockIdx.z * nby + blockIdx.y) * nbx + blockIdx.x;
        const int nwg = nbx * nby * nbz;
        const int cpx = nwg >> 3;
        const int logical = (lin & 7) * cpx + (lin >> 3);
        constexpr int CHB = CHX * CHY;
        const int chunk  = logical / CHB;
        const int within = logical % CHB;
        const int cx = within % CHX, cy = within / CHX;
        const int chunks_x = nbx / CHX;
        const int chx = chunk % chunks_x;
        int t = chunk / chunks_x;
        const int chunks_y = nby / CHY;
        const int chy = t % chunks_y;
        bz = t / chunks_y;
        bx = chx * CHX + cx;
        by = chy * CHY + cy;
    } else {
        bx = blockIdx.x; by = blockIdx.y; bz = blockIdx.z;
    }

    const int tid  = threadIdx.x;
    const int wave = tid >> 6, lane = tid & 63;
    const int wm = (wave >> 1) * (WM * 16);
    const int wn = (wave & 1) * (WN * 16);
    const int fr = lane & 15;
    const int fk = (lane >> 4) * 8;
    const int srow = lane >> 2;
    const int scol = (lane & 3) * 8;

    const long mBlock = (long)by * BM;
    const long nBlock = (long)bx * BN;
    const int zz = bz;
    const int z   = QK ? (zz & 3) : zz;
    const int sel = QK ? (zz >> 2) : 0;
    const f16_t* Az = Ah + (size_t)z * sAz + (size_t)sel * sAw;
    const f16_t* Bz = Bh + (size_t)z * sBz + (size_t)sel * sBw;
    const float* biasp = bias ? (bias + (QK ? sel * C_DIM : 0)) : nullptr;

    const f16_t* gA = Az + (size_t)(mBlock + srow) * lda + scol;
    const f16_t* gB = Bz + (size_t)(nBlock + srow) * lda + scol;

    const f16_t* srcA[AOPS]; int dstA[AOPS];
    const f16_t* srcB[BOPS]; int dstB[BOPS];
#pragma unroll
    for (int i = 0; i < AOPS; i++) {
        int seg = i * 4 + wave;
        srcA[i] = gA + (size_t)seg * 16 * lda;
        dstA[i] = seg * 512;
    }
#pragma unroll
    for (int i = 0; i < BOPS; i++) {
        int seg = i * 4 + wave;
        srcB[i] = gB + (size_t)seg * 16 * lda;
        dstB[i] = BM * BK + seg * 512;
    }

    auto stage = [&](int t) {
        f16_t* dst = smem + (t % 3) * BUFSZ;
        const int k0 = t * BK;
#pragma unroll
        for (int i = 0; i < AOPS; i++) g2l16(srcA[i] + k0, dst + dstA[i]);
#pragma unroll
        for (int i = 0; i < BOPS; i++) g2l16(srcB[i] + k0, dst + dstB[i]);
    };

    f32x4 acc[WM][WN];
#pragma unroll
    for (int i = 0; i < WM; i++)
#pragma unroll
        for (int j = 0; j < WN; j++)
            acc[i][j] = (f32x4){0.f, 0.f, 0.f, 0.f};

    stage(0);
    stage(1);
    vmwait<OPS>();
    __builtin_amdgcn_s_barrier();
    __builtin_amdgcn_sched_barrier(0);

#pragma unroll
    for (int t = 0; t < NIT; ++t) {
        if (t + 2 < NIT) stage(t + 2);
        const f16_t* sA = smem + (t % 3) * BUFSZ;
        const f16_t* sB = sA + BM * BK;
        f16x8 af[WM], bf[WN];
#pragma unroll
        for (int i = 0; i < WM; i++)
            af[i] = *reinterpret_cast<const f16x8*>(sA + (wm + i * 16 + fr) * BK + fk);
#pragma unroll
        for (int j = 0; j < WN; j++)
            bf[j] = *reinterpret_cast<const f16x8*>(sB + (wn + j * 16 + fr) * BK + fk);
#pragma unroll
        for (int i = 0; i < WM; i++)
#pragma unroll
            for (int j = 0; j < WN; j++)
                acc[i][j] = mfma_f16(af[i], bf[j], acc[i][j]);

        if (t + 2 < NIT)      vmwait<OPS>();
        else if (t + 1 < NIT) vmwait<0>();
        if (t + 1 < NIT) {
            __builtin_amdgcn_s_barrier();
            __builtin_amdgcn_sched_barrier(0);
        }
    }

    const int col  = lane & 15;
    const int rowq = (lane >> 4) * 4;
    const size_t cbase = (size_t)z * sCz + (size_t)sel * sCw;
#pragma unroll
    for (int i = 0; i < WM; i++) {
        const long mb = mBlock + wm + i * 16 + rowq;
        float bv[4];
#pragma unroll
        for (int r = 0; r < 4; r++) bv[r] = biasp ? biasp[mb + r] : 0.0f;
#pragma unroll
        for (int j = 0; j < WN; j++) {
            const long n = nBlock + wn + j * 16 + col;
            float v[4];
#pragma unroll
            for (int r = 0; r < 4; r++) v[r] = acc[i][j][r] + bv[r];
            if constexpr (EPI == 0) {
                float* O = (float*)Cout0 + cbase;
                const float* R = resid ? (resid + (size_t)z * sRz) : nullptr;
#pragma unroll
                for (int r = 0; r < 4; r++) {
                    size_t off = (size_t)(mb + r) * ldc + n;
                    O[off] = v[r] + (R ? R[off] : 0.0f);
                }
            } else if constexpr (EPI == 1) {
                f16_t* O = (f16_t*)Cout0 + cbase;
#pragma unroll
                for (int r = 0; r < 4; r++) O[(size_t)(mb + r) * ldc + n] = (f16_t)v[r];
            } else if constexpr (EPI == 3) {
                alignas(8) f16_t h[4];
#pragma unroll
                for (int r = 0; r < 4; r++) h[r] = (f16_t)v[r];
                size_t offo = cbase + (size_t)n * ldc + mb;
                *reinterpret_cast<uint2*>((f16_t*)Cout0 + offo) = *reinterpret_cast<uint2*>(h);
            } else {
                alignas(16) float h[4];
#pragma unroll
                for (int r = 0; r < 4; r++) h[r] = v[r];
                size_t offo = cbase + (size_t)n * ldc + mb;
                *reinterpret_cast<float4*>((float*)Cout0 + offo) = *reinterpret_cast<float4*>(h);
            }
        }
    }
}

// ---------------------------------------------------------------------------
extern "C" void kernel_launch(void* const* d_in, const int* in_sizes, int n_in,
                              void* d_out, int out_size, void* d_ws, size_t ws_size,
                              hipStream_t stream)
{
    const float* x_fcc = (const float*)d_in[0];
    const float* x_fss = (const float*)d_in[1];
    const float* w1 = (const float*)d_in[2];
    const float* b1 = (const float*)d_in[3];
    const float* w2 = (const float*)d_in[4];
    const float* b2 = (const float*)d_in[5];
    const float* w3 = (const float*)d_in[6];
    const float* b3 = (const float*)d_in[7];
    const float* wrs = (const float*)d_in[8];
    const float* brs = (const float*)d_in[9];
    float* out = (float*)d_out;
    (void)n_in; (void)in_sizes; (void)out_size; (void)ws_size;

    char* base = (char*)d_ws;
    size_t off = 0;
    auto take = [&](size_t bytes) -> char* {
        char* p = base + off;
        off += (bytes + 255) & ~(size_t)255;
        return p;
    };
    const size_t WB = (size_t)C_DIM * C_DIM * sizeof(f16_t);    // 512 KB
    const size_t TB = (size_t)NBATCH * CHW * sizeof(f16_t);     // 16 MB
    const long  TBe = NBATCH * CHW;                             // 8388608 elems

    float* meanc = (float*)take(2048 * 4);
    float* rstdc = (float*)take(2048 * 4);
    float* means = (float*)take(2048 * 4);
    float* rstds = (float*)take(2048 * 4);
    float* biasws = (float*)take(4 * C_DIM * 4);
    f16_t* w1h = (f16_t*)take(WB);
    f16_t* w2h = (f16_t*)take(WB);
    f16_t* w3h = (f16_t*)take(WB);
    f16_t* wrh = (f16_t*)take(WB);
    f16_t* qT = (f16_t*)take(TB);
    f16_t* kT = (f16_t*)take(TB);
    f16_t* vh   = (f16_t*)take(TB);
    f16_t* frsT = (f16_t*)take(TB);
    // 128 MB region. phase-1: xcT(16) xsT(16) xsrT(16) [dead after convs].
    // per-batch attention: S fp32 [0,64) -> P fp16 [64,96) -> PV partials
    // fp32 x8 [0,64) (S dead) -> reduce8 -> frsT.
    char* packb = take(8 * TB);
    f16_t* xcT  = (f16_t*)(packb);
    f16_t* xsT  = (f16_t*)(packb + TB);
    f16_t* xsrT = (f16_t*)(packb + 2 * TB);
    float* Smat = (float*)(packb);
    f16_t* Pmat = (f16_t*)(packb + 4 * TB);
    float* Part = (float*)(packb);          // overwrites dead S
    // total ws unchanged (~194 MB)

    dim3 blk(256);
    dim3 blk5(512);

    // 1. stats
    stats_kernel<<<dim3(4096), blk, 0, stream>>>(x_fcc, x_fss, meanc, rstdc, means, rstds);
    // 2. weight packs + bias copy
    pack_w4_kernel<<<dim3(1024, 4), blk, 0, stream>>>(
        w1, w2, w3, wrs, w1h, w2h, w3h, wrh, b1, b2, b3, brs, biasws);
    // 3. input packs
    pack_T_kernel<<<dim3(128, 16, 12), blk, 0, stream>>>(
        x_fcc, x_fss, meanc, rstdc, means, rstds, xcT, xsT, xsrT);
    // 4. q+k convs merged (new engine): sel 0 = (w1,content)->qT; 1 = (w2,style)->kT
    gemm256<3, true, 8, 2><<<dim3(32, 2, 8), blk5, 0, stream>>>(
        w1h, xcT, qT, biasws, C_DIM, C_DIM,
        0L, CHW, CHW, (long)C_DIM * C_DIM, TBe, TBe);
    // 5. v conv (old engine): [c][p] layout
    gemm_nt<4, 4, 1, false, C_DIM, 16, 4><<<dim3(32, 4, 4), blk, 0, stream>>>(
        w3h, xsrT, vh, biasws + 2 * C_DIM, nullptr, C_DIM, HW_DIM,
        0L, CHW, CHW, 0L, 0L, 0L, 0L);
    // 6. per-batch attention
    for (int b = 0; b < NBATCH; b++) {
        // scores: S[q][k] (new engine, 512 blocks, 1/CU x 2 rounds)
        gemm256<0, false, 8, 4><<<dim3(32, 16, 1), blk5, 0, stream>>>(
            qT + (size_t)b * CHW, kT + (size_t)b * CHW,
            Smat, nullptr, C_DIM, HW_DIM,
            0L, 0L, 0L, 0L, 0L, 0L);
        softmax_rows<<<dim3(4096), blk, 0, stream>>>(Smat, Pmat);
        // PV split-8: z = split (k-offset z*512), partial[z] fp32 [q][c]
        gemm256<4, false, 8, 2><<<dim3(32, 2, 8), blk5, 0, stream>>>(
            vh + (size_t)b * CHW, Pmat,
            Part, nullptr, HW_DIM, C_DIM,
            512L, 512L, (long)CHW, 0L, 0L, 0L);
        // reduce 8 partials -> fp16 frsT[b]
        reduce8_kernel<<<dim3(CHW / 1024), blk, 0, stream>>>(
            Part, frsT + (size_t)b * CHW);
    }
    // 7. final conv + bias + residual -> fp32 out (old engine)
    gemm_nt<4, 4, 0, false, C_DIM, 16, 4><<<dim3(32, 4, 4), blk, 0, stream>>>(
        wrh, frsT, out, biasws + 3 * C_DIM, x_fcc, C_DIM, HW_DIM,
        0L, CHW, CHW, CHW, 0L, 0L, 0L);
}

// Round 5
// 533.408 us; speedup vs baseline: 1.1549x; 1.0459x over previous
//
#include <hip/hip_runtime.h>
#include <hip/hip_bf16.h>

// SA_fusion: B=4, C=512, H=W=64 (HW=4096), fp32 in/out.
// R11: consolidate on the gemm256 engine. R10 post-mortem: (a) PV split-8
// doubled partial traffic vs split-4 (+256MB total ~= +40us, ate half the
// engine gain) -- NT is now a template param so PV runs split-4/NT=16
// (grid 256 = 1 block/CU) with the proven fp32 reduce4; (b) v conv + final
// conv were still on the old ~390TF engine -- ported to gemm256 (EPI=1,
// EPI=0+bias+resid), gemm_nt deleted; (c) pack_T read the style input
// twice (norm + raw passes) -- fused to one read writing both (saves
// 64MB HBM read). Engine itself unchanged from R10 (ring-3, 2-phase/tile,
// vmcnt(6) counted, T2 granule-XOR swizzle, T5 setprio).

typedef _Float16 f16_t;
typedef _Float16 f16x8 __attribute__((ext_vector_type(8)));
typedef float f32x4 __attribute__((ext_vector_type(4)));

#define C_DIM 512
#define HW_DIM 4096
#define NBATCH 4
#define CHW (512L * 4096L)

__device__ inline f32x4 mfma_f16(f16x8 a, f16x8 b, f32x4 c) {
    return __builtin_amdgcn_mfma_f32_16x16x32_f16(a, b, c, 0, 0, 0);
}

// async 16B/lane global->LDS; lane i lands at base + i*16 (wave-uniform base).
__device__ inline void g2l16(const f16_t* g, f16_t* l) {
    auto gp = (const __attribute__((address_space(1))) uint32_t*)(uintptr_t)g;
    auto lp = (__attribute__((address_space(3))) uint32_t*)(uint32_t)(uintptr_t)l;
    __builtin_amdgcn_global_load_lds(gp, lp, 16, 0, 0);
}

// counted vmcnt wait, compile-time immediate, memory-clobbered.
template<int N> __device__ inline void vmwait() {
    static_assert(N == 0 || N == 6, "add vmcnt case");
    if constexpr (N == 0) asm volatile("s_waitcnt vmcnt(0)" ::: "memory");
    else                  asm volatile("s_waitcnt vmcnt(6)" ::: "memory");
}

__device__ inline void barrier_mem() {
    asm volatile("s_barrier" ::: "memory");
    __builtin_amdgcn_sched_barrier(0);
}

// ---------------- stats: mean + rstd (unbiased var, ddof=1) per (b,c) --------
__global__ __launch_bounds__(256) void stats_kernel(
    const float* __restrict__ xc, const float* __restrict__ xs,
    float* __restrict__ meanc, float* __restrict__ rstdc,
    float* __restrict__ means, float* __restrict__ rstds)
{
    int id = blockIdx.x;
    int bc = id & 2047;
    const float4* x = (const float4*)((id < 2048 ? xc : xs) + (size_t)bc * HW_DIM);
    int tid = threadIdx.x;
    float s = 0.f, ss = 0.f;
#pragma unroll
    for (int i = 0; i < 4; i++) {
        float4 v = x[tid + (i << 8)];
        s += v.x + v.y + v.z + v.w;
        ss += v.x * v.x + v.y * v.y + v.z * v.z + v.w * v.w;
    }
#pragma unroll
    for (int o = 32; o; o >>= 1) { s += __shfl_down(s, o); ss += __shfl_down(ss, o); }
    __shared__ float red[8];
    if ((tid & 63) == 0) { red[(tid >> 6) * 2] = s; red[(tid >> 6) * 2 + 1] = ss; }
    __syncthreads();
    if (tid == 0) {
        s  = red[0] + red[2] + red[4] + red[6];
        ss = red[1] + red[3] + red[5] + red[7];
        float mean = s * (1.0f / 4096.0f);
        float var  = (ss - 4096.0f * mean * mean) * (1.0f / 4095.0f);
        float rstd = rsqrtf(var + 1e-5f);
        if (id < 2048) { meanc[bc] = mean; rstdc[bc] = rstd; }
        else           { means[bc] = mean; rstds[bc] = rstd; }
    }
}

// ---------------- weight pack: fp32 -> fp16 + bias copy ----------------------
__global__ __launch_bounds__(256) void pack_w4_kernel(
    const float* __restrict__ w0, const float* __restrict__ w1,
    const float* __restrict__ w2, const float* __restrict__ w3,
    f16_t* __restrict__ h0, f16_t* __restrict__ h1,
    f16_t* __restrict__ h2, f16_t* __restrict__ h3,
    const float* __restrict__ bb0, const float* __restrict__ bb1,
    const float* __restrict__ bb2, const float* __restrict__ bb3,
    float* __restrict__ biasws)
{
    int which = blockIdx.y;
    const float* w = which == 0 ? w0 : which == 1 ? w1 : which == 2 ? w2 : w3;
    f16_t* h = which == 0 ? h0 : which == 1 ? h1 : which == 2 ? h2 : h3;
    const float* bs = which == 0 ? bb0 : which == 1 ? bb1 : which == 2 ? bb2 : bb3;
    int i = blockIdx.x * 256 + threadIdx.x;
    h[i] = (f16_t)w[i];
    if (i < C_DIM) biasws[which * C_DIM + i] = bs[i];
}

// ---------------- input pack: (B,C,HW) fp32 -> (B,HW,C) fp16 -----------------
// src 0: content -> ch (normed). src 1: style -> sh (normed) AND sraw (raw)
// in ONE read pass (norm applied on the transposed write side, where the
// thread's column == channel).
__global__ __launch_bounds__(256) void pack_T_kernel(
    const float* __restrict__ xc, const float* __restrict__ xs,
    const float* __restrict__ meanc, const float* __restrict__ rstdc,
    const float* __restrict__ means, const float* __restrict__ rstds,
    f16_t* __restrict__ ch, f16_t* __restrict__ sh, f16_t* __restrict__ sraw)
{
    __shared__ float tile[32][33];
    int z = blockIdx.z;
    int b = z & 3, src = z >> 2;
    const float* x    = (src == 0) ? xc : xs;
    const float* mean = (src == 0) ? meanc : means;
    const float* rstd = (src == 0) ? rstdc : rstds;

    int c0 = blockIdx.y * 32, p0 = blockIdx.x * 32;
    int tp = threadIdx.x & 31, tc8 = threadIdx.x >> 5;
    const float* xb = x + ((size_t)b * C_DIM + c0) * HW_DIM + p0;
#pragma unroll
    for (int it = 0; it < 4; it++) {
        int c = tc8 + it * 8;
        tile[c][tp] = xb[(size_t)c * HW_DIM + tp];
    }
    __syncthreads();
    int wc = threadIdx.x & 31, wp8 = threadIdx.x >> 5;
    float m = mean[b * C_DIM + c0 + wc];
    float r = rstd[b * C_DIM + c0 + wc];
    size_t obase = ((size_t)b * HW_DIM + p0) * C_DIM + c0;
    f16_t* ohb = ((src == 0) ? ch : sh) + obase;
    f16_t* srb = sraw + obase;
#pragma unroll
    for (int it = 0; it < 4; it++) {
        int p = wp8 + it * 8;
        float v = tile[wc][p];
        ohb[(size_t)p * C_DIM + wc] = (f16_t)((v - m) * r);
        if (src == 1) srb[(size_t)p * C_DIM + wc] = (f16_t)v;
    }
}

// ---------------- row softmax: S fp32 (4096x4096) -> P fp16, normalized ------
__global__ __launch_bounds__(256) void softmax_rows(
    const float* __restrict__ S, f16_t* __restrict__ P)
{
    int row = blockIdx.x;
    int tid = threadIdx.x;
    int wave = tid >> 6, lane = tid & 63;
    const float4* sr = (const float4*)(S + (size_t)row * HW_DIM);
    float4 v[4];
    float mx = -3.4e38f;
#pragma unroll
    for (int i = 0; i < 4; i++) {
        v[i] = sr[tid + (i << 8)];
        mx = fmaxf(mx, fmaxf(fmaxf(v[i].x, v[i].y), fmaxf(v[i].z, v[i].w)));
    }
#pragma unroll
    for (int o = 32; o; o >>= 1) mx = fmaxf(mx, __shfl_down(mx, o));
    __shared__ float red[4];
    if (lane == 0) red[wave] = mx;
    __syncthreads();
    mx = fmaxf(fmaxf(red[0], red[1]), fmaxf(red[2], red[3]));
    float sum = 0.f;
#pragma unroll
    for (int i = 0; i < 4; i++) {
        v[i].x = __expf(v[i].x - mx); v[i].y = __expf(v[i].y - mx);
        v[i].z = __expf(v[i].z - mx); v[i].w = __expf(v[i].w - mx);
        sum += v[i].x + v[i].y + v[i].z + v[i].w;
    }
#pragma unroll
    for (int o = 32; o; o >>= 1) sum += __shfl_down(sum, o);
    __syncthreads();
    if (lane == 0) red[wave] = sum;
    __syncthreads();
    sum = red[0] + red[1] + red[2] + red[3];
    float inv = 1.0f / sum;
    uint2* pr = (uint2*)(P + (size_t)row * HW_DIM);
#pragma unroll
    for (int i = 0; i < 4; i++) {
        union { uint2 u; f16_t h[4]; } o;
        o.h[0] = (f16_t)(v[i].x * inv); o.h[1] = (f16_t)(v[i].y * inv);
        o.h[2] = (f16_t)(v[i].z * inv); o.h[3] = (f16_t)(v[i].w * inv);
        pr[tid + (i << 8)] = o.u;
    }
}

// ---------------- split-K reduce: frsT[q][c] = f16(sum of 4 fp32 partials) ---
__global__ __launch_bounds__(256) void reduce4_kernel(
    const float* __restrict__ part, f16_t* __restrict__ out)
{
    size_t i = (size_t)blockIdx.x * 256 + threadIdx.x;   // float4 index
    const float4* p0 = (const float4*)part;
    const float4* p1 = (const float4*)(part + CHW);
    const float4* p2 = (const float4*)(part + 2 * CHW);
    const float4* p3 = (const float4*)(part + 3 * CHW);
    float4 a = p0[i], b = p1[i], c = p2[i], d = p3[i];
    union { uint2 u; f16_t h[4]; } o;
    o.h[0] = (f16_t)(a.x + b.x + c.x + d.x);
    o.h[1] = (f16_t)(a.y + b.y + c.y + d.y);
    o.h[2] = (f16_t)(a.z + b.z + c.z + d.z);
    o.h[3] = (f16_t)(a.w + b.w + c.w + d.w);
    ((uint2*)out)[i] = o.u;
}

// ================= gemm256: phase-pipelined NT GEMM ==========================
// C[m][n] = sum_k A[m][k]*B[n][k]. BM=256, BN=128, BK=64, 512 threads
// (8 waves: 2 M-groups x 4 N-groups; per-wave output 128x32, acc[8][2]).
// K = NT*64. Ring-3 LDS (144KB, 1 block/CU). Per K-tile: 2 phases, each
// {ds_read frags; stage half of tile t+2; [vmcnt(6) @p1]; barrier;
// setprio(1); 16 MFMA; setprio(0); barrier}. Staging instrs cover 8 rows x
// 128B (full cache lines). T2 LDS swizzle: slot (row,g) holds source
// granule g^(row&7); write side = pre-swizzled per-lane GLOBAL source with
// linear LDS dest (rule #21); read side XORs the granule.
// EPI: 0 fp32 [m][n] (+bias,+resid); 1 f16 [m][n] (+bias);
//      3 f16 T [n][m] (+bias); 4 fp32 T [n][m] (no bias).
// QK: z encodes (sel=z>>2, batch=z&3).
template<int EPI, bool QK, int NT, int CHX, int CHY>
__global__ __launch_bounds__(512, 2) void gemm256(
    const f16_t* __restrict__ Ah, const f16_t* __restrict__ Bh,
    void* __restrict__ Cout0, const float* __restrict__ bias,
    const float* __restrict__ resid,
    int lda, int ldc,
    long sAz, long sBz, long sCz, long sRz, long sAw, long sBw, long sCw)
{
    constexpr int AE = 256 * 64;        // A elems/tile = 16384 (32KB)
    constexpr int BE = 128 * 64;        // B elems/tile = 8192  (16KB)
    constexpr int BUFE = AE + BE;       // 24576 elems = 48KB/slot
    __shared__ __align__(16) f16_t smem[3 * BUFE];   // 144KB

    // ---- XCD chunk swizzle (bijective; nwg % 8 == 0, pow2 chunks) ----
    int bx, by, bz;
    {
        const int nbx = gridDim.x, nby = gridDim.y, nbz = gridDim.z;
        const int lin = ((int)blockIdx.z * nby + blockIdx.y) * nbx + blockIdx.x;
        const int nwg = nbx * nby * nbz;
        const int cpx = nwg >> 3;
        const int logical = (lin & 7) * cpx + (lin >> 3);
        constexpr int CHB = CHX * CHY;
        const int chunk  = logical / CHB;
        const int within = logical % CHB;
        const int cx = within % CHX, cy = within / CHX;
        const int chunks_x = nbx / CHX;
        const int chx = chunk % chunks_x;
        int tt = chunk / chunks_x;
        const int chunks_y = nby / CHY;
        bz = tt / chunks_y;
        by = (tt % chunks_y) * CHY + cy;
        bx = chx * CHX + cx;
    }

    const int tid  = threadIdx.x;
    const int wave = tid >> 6, lane = tid & 63;
    const int wm = (wave >> 2) * 128;    // M-group rows
    const int wn = (wave & 3) * 32;      // N-group cols
    const int fr = lane & 15;
    const int g16 = lane >> 4;           // 0..3, frag k-granule base
    const int key = fr & 7;              // read-side swizzle key

    const int z   = QK ? (bz & 3) : bz;
    const int sel = QK ? (bz >> 2) : 0;
    const f16_t* Az = Ah + (size_t)z * sAz + (size_t)sel * sAw;
    const f16_t* Bz = Bh + (size_t)z * sBz + (size_t)sel * sBw;
    const float* biasp = bias ? (bias + (QK ? sel * C_DIM : 0)) : nullptr;
    const long mBlock = (long)by * 256;
    const long nBlock = (long)bx * 128;

    // staging: per instr 8 rows x 128B; lane l -> row +(l>>3), LDS granule
    // l&7; pre-swizzled source granule (l&7)^(l>>3)  [slot g <- src g^(row&7)]
    const int srow8 = lane >> 3;
    const int gsrc  = ((lane & 7) ^ srow8) * 8;   // f16 elems
    const f16_t* aSrc[4]; const f16_t* bSrc[2];
    int aDst[4], bDst[2];
#pragma unroll
    for (int q = 0; q < 4; q++) {
        int j = 4 * wave + q;
        aSrc[q] = Az + (size_t)(mBlock + 8 * j + srow8) * lda + gsrc;
        aDst[q] = j * 512;
    }
#pragma unroll
    for (int q = 0; q < 2; q++) {
        int j = 2 * wave + q;
        bSrc[q] = Bz + (size_t)(nBlock + 8 * j + srow8) * lda + gsrc;
        bDst[q] = AE + j * 512;
    }

    auto stageA = [&](int t) {
        f16_t* dst = smem + (t % 3) * BUFE;
        const int k0 = t * 64;
#pragma unroll
        for (int q = 0; q < 4; q++) g2l16(aSrc[q] + k0, dst + aDst[q]);
    };
    auto stageB = [&](int t) {
        f16_t* dst = smem + (t % 3) * BUFE;
        const int k0 = t * 64;
#pragma unroll
        for (int q = 0; q < 2; q++) g2l16(bSrc[q] + k0, dst + bDst[q]);
    };

    f32x4 acc[8][2];
#pragma unroll
    for (int i = 0; i < 8; i++)
#pragma unroll
        for (int j = 0; j < 2; j++) acc[i][j] = (f32x4){0.f, 0.f, 0.f, 0.f};

    // prologue: tiles 0,1 issued; tile 0 complete, tile 1 (6 loads) in flight
    stageA(0); stageB(0); stageA(1); stageB(1);
    vmwait<6>();
    barrier_mem();

#pragma unroll
    for (int t = 0; t < NT; ++t) {
        const f16_t* buf = smem + (t % 3) * BUFE;
#pragma unroll
        for (int ks = 0; ks < 2; ++ks) {
            f16x8 a[8], b[2];
            const int gr = ((ks * 4 + g16) ^ key) * 8;   // swizzled granule
#pragma unroll
            for (int j2 = 0; j2 < 2; j2++)
                b[j2] = *reinterpret_cast<const f16x8*>(
                    buf + AE + (wn + j2 * 16 + fr) * 64 + gr);
#pragma unroll
            for (int mi = 0; mi < 8; mi++)
                a[mi] = *reinterpret_cast<const f16x8*>(
                    buf + (wm + mi * 16 + fr) * 64 + gr);
            if (t + 2 < NT) { if (ks == 0) stageA(t + 2); else stageB(t + 2); }
            if (ks == 1) {
                if (t + 2 < NT)      vmwait<6>();   // t+1 landed, t+2 in flight
                else if (t + 1 < NT) vmwait<0>();   // drain for last tile
            }
            barrier_mem();
            __builtin_amdgcn_s_setprio(1);
#pragma unroll
            for (int mi = 0; mi < 8; mi++)
#pragma unroll
                for (int j2 = 0; j2 < 2; j2++)
                    acc[mi][j2] = mfma_f16(a[mi], b[j2], acc[mi][j2]);
            __builtin_amdgcn_s_setprio(0);
            barrier_mem();
        }
    }

    // epilogue. D layout: col(n)=lane&15, row(m)=(lane>>4)*4+reg
    const int col  = lane & 15;
    const int rowq = (lane >> 4) * 4;
    const size_t cbase = (size_t)z * sCz + (size_t)sel * sCw;
#pragma unroll
    for (int mi = 0; mi < 8; mi++) {
        const long mb = mBlock + wm + mi * 16 + rowq;
        float bv[4];
#pragma unroll
        for (int r = 0; r < 4; r++) bv[r] = biasp ? biasp[mb + r] : 0.0f;
#pragma unroll
        for (int j2 = 0; j2 < 2; j2++) {
            const long n = nBlock + wn + j2 * 16 + col;
            float v[4];
#pragma unroll
            for (int r = 0; r < 4; r++) v[r] = acc[mi][j2][r] + bv[r];
            if constexpr (EPI == 0) {
                float* O = (float*)Cout0 + cbase;
                const float* R = resid ? (resid + (size_t)z * sRz) : nullptr;
#pragma unroll
                for (int r = 0; r < 4; r++) {
                    size_t off = (size_t)(mb + r) * ldc + n;
                    O[off] = v[r] + (R ? R[off] : 0.0f);
                }
            } else if constexpr (EPI == 1) {
                f16_t* O = (f16_t*)Cout0 + cbase;
#pragma unroll
                for (int r = 0; r < 4; r++) O[(size_t)(mb + r) * ldc + n] = (f16_t)v[r];
            } else if constexpr (EPI == 3) {
                alignas(8) f16_t h[4];
#pragma unroll
                for (int r = 0; r < 4; r++) h[r] = (f16_t)v[r];
                *reinterpret_cast<uint2*>((f16_t*)Cout0 + cbase + (size_t)n * ldc + mb)
                    = *reinterpret_cast<uint2*>(h);
            } else {   // EPI == 4: fp32 transposed partial
                alignas(16) float h[4];
#pragma unroll
                for (int r = 0; r < 4; r++) h[r] = v[r];
                *reinterpret_cast<float4*>((float*)Cout0 + cbase + (size_t)n * ldc + mb)
                    = *reinterpret_cast<float4*>(h);
            }
        }
    }
}

// ---------------------------------------------------------------------------
extern "C" void kernel_launch(void* const* d_in, const int* in_sizes, int n_in,
                              void* d_out, int out_size, void* d_ws, size_t ws_size,
                              hipStream_t stream)
{
    const float* x_fcc = (const float*)d_in[0];
    const float* x_fss = (const float*)d_in[1];
    const float* w1 = (const float*)d_in[2];
    const float* b1 = (const float*)d_in[3];
    const float* w2 = (const float*)d_in[4];
    const float* b2 = (const float*)d_in[5];
    const float* w3 = (const float*)d_in[6];
    const float* b3 = (const float*)d_in[7];
    const float* wrs = (const float*)d_in[8];
    const float* brs = (const float*)d_in[9];
    float* out = (float*)d_out;
    (void)n_in; (void)in_sizes; (void)out_size; (void)ws_size;

    char* base = (char*)d_ws;
    size_t off = 0;
    auto take = [&](size_t bytes) -> char* {
        char* p = base + off;
        off += (bytes + 255) & ~(size_t)255;
        return p;
    };
    const size_t WB = (size_t)C_DIM * C_DIM * sizeof(f16_t);    // 512 KB
    const size_t TB = (size_t)NBATCH * CHW * sizeof(f16_t);     // 16 MB
    const long  TBe = NBATCH * CHW;                             // 8388608 elems

    float* meanc = (float*)take(2048 * 4);
    float* rstdc = (float*)take(2048 * 4);
    float* means = (float*)take(2048 * 4);
    float* rstds = (float*)take(2048 * 4);
    float* biasws = (float*)take(4 * C_DIM * 4);
    f16_t* w1h = (f16_t*)take(WB);
    f16_t* w2h = (f16_t*)take(WB);
    f16_t* w3h = (f16_t*)take(WB);
    f16_t* wrh = (f16_t*)take(WB);
    f16_t* qT = (f16_t*)take(TB);
    f16_t* kT = (f16_t*)take(TB);
    f16_t* vh   = (f16_t*)take(TB);
    f16_t* frsT = (f16_t*)take(TB);
    // 128 MB region. phase-1: xcT(16) xsT(16) xsrT(16) [dead after convs].
    // per-batch attention: S fp32 [0,64) -> P fp16 [64,96) -> PV partials
    // fp32 x4 [96,128) -> reduce4 -> frsT.
    char* packb = take(8 * TB);
    f16_t* xcT  = (f16_t*)(packb);
    f16_t* xsT  = (f16_t*)(packb + TB);
    f16_t* xsrT = (f16_t*)(packb + 2 * TB);
    float* Smat = (float*)(packb);
    f16_t* Pmat = (f16_t*)(packb + 4 * TB);
    float* Part = (float*)(packb + 6 * TB);
    // total ws unchanged (~194 MB)

    dim3 blk(256);
    dim3 blk5(512);

    // 1. stats
    stats_kernel<<<dim3(4096), blk, 0, stream>>>(x_fcc, x_fss, meanc, rstdc, means, rstds);
    // 2. weight packs + bias copy
    pack_w4_kernel<<<dim3(1024, 4), blk, 0, stream>>>(
        w1, w2, w3, wrs, w1h, w2h, w3h, wrh, b1, b2, b3, brs, biasws);
    // 3. input packs (single style read -> sh + sraw)
    pack_T_kernel<<<dim3(128, 16, 8), blk, 0, stream>>>(
        x_fcc, x_fss, meanc, rstdc, means, rstds, xcT, xsT, xsrT);
    // 4. q+k convs merged: sel 0 = (w1,content)->qT; 1 = (w2,style)->kT
    gemm256<3, true, 8, 8, 2><<<dim3(32, 2, 8), blk5, 0, stream>>>(
        w1h, xcT, qT, biasws, nullptr, C_DIM, C_DIM,
        0L, CHW, CHW, 0L, (long)C_DIM * C_DIM, TBe, TBe);
    // 5. v conv: vh[c][p] f16 +bias
    gemm256<1, false, 8, 8, 2><<<dim3(32, 2, 4), blk5, 0, stream>>>(
        w3h, xsrT, vh, biasws + 2 * C_DIM, nullptr, C_DIM, HW_DIM,
        0L, CHW, CHW, 0L, 0L, 0L, 0L);
    // 6. per-batch attention
    for (int b = 0; b < NBATCH; b++) {
        // scores: S[q][k] fp32 (512 blocks)
        gemm256<0, false, 8, 8, 4><<<dim3(32, 16, 1), blk5, 0, stream>>>(
            qT + (size_t)b * CHW, kT + (size_t)b * CHW,
            Smat, nullptr, nullptr, C_DIM, HW_DIM,
            0L, 0L, 0L, 0L, 0L, 0L, 0L);
        softmax_rows<<<dim3(4096), blk, 0, stream>>>(Smat, Pmat);
        // PV split-4: z = split (k-offset z*1024, NT=16), partial[z] fp32 [q][c]
        gemm256<4, false, 16, 8, 2><<<dim3(32, 2, 4), blk5, 0, stream>>>(
            vh + (size_t)b * CHW, Pmat,
            Part, nullptr, nullptr, HW_DIM, C_DIM,
            1024L, 1024L, CHW, 0L, 0L, 0L, 0L);
        // reduce 4 partials -> fp16 frsT[b]
        reduce4_kernel<<<dim3(CHW / 1024), blk, 0, stream>>>(
            Part, frsT + (size_t)b * CHW);
    }
    // 7. final conv + bias + residual -> fp32 out
    gemm256<0, false, 8, 8, 2><<<dim3(32, 2, 4), blk5, 0, stream>>>(
        wrh, frsT, out, biasws + 3 * C_DIM, x_fcc, C_DIM, HW_DIM,
        0L, CHW, CHW, CHW, 0L, 0L, 0L);
}